// Round 2
// baseline (432.886 us; speedup 1.0000x reference)
//
#include <hip/hip_runtime.h>
#include <hip/hip_bf16.h>

// dims
// B=16 W=32 M=512 NH=64 HALF=32 K=8 H=8 LK=16 LOUT=2 NSP=10 GCIN=24
// rows = B*M = 8192
// All reference dtypes are float32 — inputs and output are fp32.

// ---------------- K1: RNN -------------------------------------------------
// one wave per (b,m) series; lane = hidden index; Whh row in regs;
// cross-lane h via readlane (uniform k).
__global__ __launch_bounds__(256) void rnn_kernel(
    const float* __restrict__ x, const float* __restrict__ Wih,
    const float* __restrict__ Whh, const float* __restrict__ bih,
    const float* __restrict__ bhh, float* __restrict__ lh)
{
    int wid  = threadIdx.x >> 6;
    int lane = threadIdx.x & 63;
    int row  = blockIdx.x * 4 + wid;       // 0..8191
    int b    = row >> 9;
    int m    = row & 511;

    float whh[64];
#pragma unroll
    for (int k = 0; k < 64; ++k) whh[k] = Whh[lane * 64 + k];
    float wih = Wih[lane];
    float bb  = bih[lane] + bhh[lane];

    __shared__ float sq[4][32];
    if (lane < 32) sq[wid][lane] = x[(b * 32 + lane) * 512 + m];
    __syncthreads();

    float h = 0.f;
    for (int t = 0; t < 32; ++t) {
        float acc = sq[wid][t] * wih + bb;
#pragma unroll
        for (int k = 0; k < 64; ++k) {
            float hk = __uint_as_float(
                __builtin_amdgcn_readlane(__float_as_uint(h), k));
            acc += hk * whh[k];
        }
        h = tanhf(acc);
    }
    lh[row * 64 + lane] = h;
}

// ---------------- K2: e1 = lh@W1^T, e2 = lh@W2^T --------------------------
__global__ __launch_bounds__(256) void e_kernel(
    const float* __restrict__ lh, const float* __restrict__ W1,
    const float* __restrict__ W2, float* __restrict__ e1, float* __restrict__ e2)
{
    int wid  = threadIdx.x >> 6;
    int lane = threadIdx.x & 63;
    int row  = blockIdx.x * 4 + wid;
    int hh   = lane & 31;
    const float* Wm = (lane < 32) ? W1 : W2;
    const float* hr = lh + row * 64;
    float acc = 0.f;
#pragma unroll
    for (int n = 0; n < 64; ++n) acc += hr[n] * Wm[hh * 64 + n];
    float* dst = (lane < 32) ? e1 : e2;
    dst[row * 32 + hh] = acc;
}

// ---------------- K3: a_mx[b,i,j] = V.elu(e2_i + e1_j + b1) + bv ----------
__global__ __launch_bounds__(256) void amx_kernel(
    const float* __restrict__ e1, const float* __restrict__ e2,
    const float* __restrict__ b1p, const float* __restrict__ Vp,
    const float* __restrict__ bvp, float* __restrict__ amx)
{
    int bb = blockIdx.z;
    int i0 = blockIdx.y * 16, j0 = blockIdx.x * 16;
    int ti = threadIdx.x >> 4, tj = threadIdx.x & 15;
    __shared__ float e2s[16][33], e1s[16][33], b1s[32], Vs[32];
    int t = threadIdx.x;
    for (int q = t; q < 512; q += 256) {
        int r = q >> 5, c = q & 31;
        e2s[r][c] = e2[(bb * 512 + i0 + r) * 32 + c];
        e1s[r][c] = e1[(bb * 512 + j0 + r) * 32 + c];
    }
    if (t < 32) { b1s[t] = b1p[t]; Vs[t] = Vp[t]; }
    __syncthreads();
    float acc = 0.f;
#pragma unroll
    for (int hh = 0; hh < 32; ++hh) {
        float v  = e2s[ti][hh] + e1s[tj][hh] + b1s[hh];
        float el = v > 0.f ? v : expm1f(v);
        acc += Vs[hh] * el;
    }
    amx[(bb * 512 + i0 + ti) * 512 + j0 + tj] = acc + bvp[0];
}

// ---------------- K4: column norms over i, then scale ---------------------
__global__ void norm_kernel(const float* __restrict__ amx, float* __restrict__ nrm)
{
    int j  = blockIdx.x * 256 + threadIdx.x;   // 0..8191 = b*512 + jj
    int bb = j >> 9, jj = j & 511;
    const float* base = amx + bb * 512 * 512 + jj;
    float s = 0.f;
    for (int i = 0; i < 512; ++i) { float v = base[i * 512]; s += v * v; }
    nrm[j] = fmaxf(sqrtf(s), 1e-12f);
}

__global__ void scale_kernel(float* __restrict__ amx, const float* __restrict__ nrm)
{
    int idx = blockIdx.x * 256 + threadIdx.x;  // 4.19M
    int bb  = idx >> 18;
    int j   = idx & 511;
    amx[idx] = amx[idx] / nrm[bb * 512 + j];
}

// ---------------- K5: c = sigmoid(amx@Wb + wb); adjmix = adj*c + amx*(1-c)
__global__ __launch_bounds__(256) void gemm_adjmix(
    const float* __restrict__ amx, const float* __restrict__ Wb,
    const float* __restrict__ wbp, const float* __restrict__ adj,
    float* __restrict__ adjmix)
{
    int bb = blockIdx.z;
    int i0 = blockIdx.y * 64, j0 = blockIdx.x * 64;
    __shared__ float As[16][65], Bs[16][65];
    int t = threadIdx.x, tx = t & 15, ty = t >> 4;
    float acc[4][4] = {};
    const float* A = amx + bb * 512 * 512;
    for (int k0 = 0; k0 < 512; k0 += 16) {
#pragma unroll
        for (int q = 0; q < 4; ++q) {
            int ii = ty + q * 16, kk = tx;
            As[kk][ii] = A[(i0 + ii) * 512 + k0 + kk];
        }
#pragma unroll
        for (int q = 0; q < 4; ++q) {
            int kk = (t >> 6) + q * 4, jj = t & 63;
            Bs[kk][jj] = Wb[(k0 + kk) * 512 + j0 + jj];
        }
        __syncthreads();
#pragma unroll
        for (int kk = 0; kk < 16; ++kk) {
            float a[4], bv[4];
#pragma unroll
            for (int q = 0; q < 4; ++q) a[q]  = As[kk][ty + q * 16];
#pragma unroll
            for (int q = 0; q < 4; ++q) bv[q] = Bs[kk][tx + q * 16];
#pragma unroll
            for (int p = 0; p < 4; ++p)
#pragma unroll
                for (int q = 0; q < 4; ++q) acc[p][q] += a[p] * bv[q];
        }
        __syncthreads();
    }
    float wb = wbp[0];
#pragma unroll
    for (int p = 0; p < 4; ++p) {
        int i = i0 + ty + p * 16;
#pragma unroll
        for (int q = 0; q < 4; ++q) {
            int j = j0 + tx + q * 16;
            float s  = acc[p][q] + wb;
            float cv = 1.f / (1.f + __expf(-s));
            float am = A[i * 512 + j];
            float ad = adj[i * 512 + j];
            adjmix[(bb * 512 + i) * 512 + j] = ad * cv + am * (1.f - cv);
        }
    }
}

// ---------------- K6: conv features r -------------------------------------
__global__ void r_kernel(
    const float* __restrict__ x, const float* __restrict__ conv_w,
    const float* __restrict__ conv_b, const float* __restrict__ convl_w,
    const float* __restrict__ convl_b, float* __restrict__ rr)
{
    int idx = blockIdx.x * 256 + threadIdx.x;  // row*8 + k, 65536
    int k   = idx & 7;
    int row = idx >> 3;
    int bb  = row >> 9, m = row & 511;
    const float* xb = x + bb * 32 * 512 + m;
    float s = conv_b[k];
    for (int w = 0; w < 32; ++w) s += xb[w * 512] * conv_w[k * 32 + w];
    float l0 = convl_b[k], l1 = l0;
    for (int tt = 0; tt < 16; ++tt) {
        float wv = convl_w[k * 16 + tt];
        l0 += xb[(2 * tt) * 512] * wv;
        l1 += xb[(2 * tt + 1) * 512] * wv;
    }
    float* dst = rr + row * 24 + k * 3;
    dst[0] = fmaxf(s, 0.f);
    dst[1] = fmaxf(l0, 0.f);
    dst[2] = fmaxf(l1, 0.f);
}

// ---------------- K7: rg = r @ gc1_w --------------------------------------
__global__ void rg_kernel(const float* __restrict__ rr,
                          const float* __restrict__ gc1_w, float* __restrict__ rg)
{
    int idx = blockIdx.x * 256 + threadIdx.x;  // row*64 + n
    int n   = idx & 63, row = idx >> 6;
    const float* r = rr + row * 24;
    float acc = 0.f;
#pragma unroll
    for (int c = 0; c < 24; ++c) acc += r[c] * gc1_w[c * 64 + n];
    rg[idx] = acc;
}

// ---------------- K8: h1 = relu(adjmix @ rg + gc1_b) ----------------------
__global__ __launch_bounds__(256) void gemm_h1(
    const float* __restrict__ adjmix, const float* __restrict__ rg,
    const float* __restrict__ gc1_b, float* __restrict__ h1)
{
    int bb = blockIdx.z;
    int i0 = blockIdx.y * 64;
    __shared__ float As[16][65], Bs[16][65];
    int t = threadIdx.x, tx = t & 15, ty = t >> 4;
    float acc[4][4] = {};
    const float* A  = adjmix + bb * 512 * 512;
    const float* Bm = rg + bb * 512 * 64;
    for (int k0 = 0; k0 < 512; k0 += 16) {
#pragma unroll
        for (int q = 0; q < 4; ++q) {
            int ii = ty + q * 16, kk = tx;
            As[kk][ii] = A[(i0 + ii) * 512 + k0 + kk];
        }
#pragma unroll
        for (int q = 0; q < 4; ++q) {
            int kk = (t >> 6) + q * 4, jj = t & 63;
            Bs[kk][jj] = Bm[(k0 + kk) * 64 + jj];
        }
        __syncthreads();
#pragma unroll
        for (int kk = 0; kk < 16; ++kk) {
            float a[4], bv[4];
#pragma unroll
            for (int q = 0; q < 4; ++q) a[q]  = As[kk][ty + q * 16];
#pragma unroll
            for (int q = 0; q < 4; ++q) bv[q] = Bs[kk][tx + q * 16];
#pragma unroll
            for (int p = 0; p < 4; ++p)
#pragma unroll
                for (int q = 0; q < 4; ++q) acc[p][q] += a[p] * bv[q];
        }
        __syncthreads();
    }
#pragma unroll
    for (int p = 0; p < 4; ++p) {
        int i = i0 + ty + p * 16;
#pragma unroll
        for (int q = 0; q < 4; ++q) {
            int j = tx + q * 16;
            h1[(bb * 512 + i) * 64 + j] = fmaxf(acc[p][q] + gc1_b[j], 0.f);
        }
    }
}

// ---------------- K9: h1g = h1 @ gc2_w ------------------------------------
__global__ void h1g_kernel(const float* __restrict__ h1,
                           const float* __restrict__ gc2_w, float* __restrict__ h1g)
{
    int idx = blockIdx.x * 256 + threadIdx.x;  // 81920 = row*10 + ns
    int row = idx / 10;
    int ns  = idx - row * 10;
    const float* hr = h1 + row * 64;
    float acc = 0.f;
#pragma unroll
    for (int n = 0; n < 64; ++n) acc += hr[n] * gc2_w[n * 10 + ns];
    h1g[idx] = acc;
}

// ---------------- K10: osp = relu(adjmix @ h1g + gc2_b) -------------------
__global__ void osp_kernel(
    const float* __restrict__ adjmix, const float* __restrict__ h1g,
    const float* __restrict__ gc2_b, float* __restrict__ osp)
{
    int bb = blockIdx.z;
    int i  = blockIdx.y * 16 + (threadIdx.x >> 4);
    int ns = threadIdx.x & 15;
    __shared__ float Bs[5120];
    for (int q = threadIdx.x; q < 5120; q += 256) Bs[q] = h1g[bb * 5120 + q];
    __syncthreads();
    if (ns < 10) {
        const float* Ar = adjmix + (bb * 512 + i) * 512;
        float acc = 0.f;
        for (int k = 0; k < 512; ++k) acc += Ar[k] * Bs[k * 10 + ns];
        osp[(bb * 512 + i) * 10 + ns] = fmaxf(acc + gc2_b[ns], 0.f);
    }
}

// ---------------- K11: out = feat @ out_w^T + out_b, transposed -----------
__global__ void out_kernel(
    const float* __restrict__ osp, const float* __restrict__ lh,
    const float* __restrict__ out_w, const float* __restrict__ out_b,
    float* __restrict__ out)
{
    int idx = blockIdx.x * 256 + threadIdx.x;  // b*4096 + h*512 + m
    int m  = idx & 511;
    int hh = (idx >> 9) & 7;
    int bb = idx >> 12;
    const float* of = osp + (bb * 512 + m) * 10;
    const float* lf = lh + (bb * 512 + m) * 64;
    float acc = out_b[hh];
#pragma unroll
    for (int n = 0; n < 10; ++n) acc += of[n] * out_w[hh * 74 + n];
#pragma unroll
    for (int n = 0; n < 64; ++n) acc += lf[n] * out_w[hh * 74 + 10 + n];
    out[idx] = acc;
}

// ---------------- launch ---------------------------------------------------
extern "C" void kernel_launch(void* const* d_in, const int* in_sizes, int n_in,
                              void* d_out, int out_size, void* d_ws, size_t ws_size,
                              hipStream_t stream)
{
    const float* x       = (const float*)d_in[0];
    const float* adj     = (const float*)d_in[1];
    const float* Wih     = (const float*)d_in[2];
    const float* Whh     = (const float*)d_in[3];
    const float* bih     = (const float*)d_in[4];
    const float* bhh     = (const float*)d_in[5];
    const float* W1      = (const float*)d_in[6];
    const float* W2      = (const float*)d_in[7];
    const float* b1      = (const float*)d_in[8];
    const float* V       = (const float*)d_in[9];
    const float* bv      = (const float*)d_in[10];
    const float* Wb      = (const float*)d_in[11];
    const float* wb      = (const float*)d_in[12];
    const float* conv_w  = (const float*)d_in[13];
    const float* conv_b  = (const float*)d_in[14];
    const float* convl_w = (const float*)d_in[15];
    const float* convl_b = (const float*)d_in[16];
    const float* gc1_w   = (const float*)d_in[17];
    const float* gc1_b   = (const float*)d_in[18];
    const float* gc2_w   = (const float*)d_in[19];
    const float* gc2_b   = (const float*)d_in[20];
    const float* out_w   = (const float*)d_in[21];
    const float* out_b   = (const float*)d_in[22];

    float* ws     = (float*)d_ws;
    float* lh     = ws;                 // 524288
    float* e1     = lh + 524288;        // 262144
    float* e2     = e1 + 262144;        // 262144
    float* amx    = e2 + 262144;        // 4194304
    float* nrm    = amx + 4194304;      // 8192
    float* adjmix = nrm + 8192;         // 4194304
    float* rr     = adjmix + 4194304;   // 196608
    float* rg     = rr + 196608;        // 524288
    float* h1     = rg + 524288;        // 524288
    float* h1g    = h1 + 524288;        // 81920
    float* osp    = h1g + 81920;        // 81920

    rnn_kernel<<<2048, 256, 0, stream>>>(x, Wih, Whh, bih, bhh, lh);
    r_kernel<<<256, 256, 0, stream>>>(x, conv_w, conv_b, convl_w, convl_b, rr);
    e_kernel<<<2048, 256, 0, stream>>>(lh, W1, W2, e1, e2);
    amx_kernel<<<dim3(32, 32, 16), 256, 0, stream>>>(e1, e2, b1, V, bv, amx);
    norm_kernel<<<32, 256, 0, stream>>>(amx, nrm);
    scale_kernel<<<16384, 256, 0, stream>>>(amx, nrm);
    gemm_adjmix<<<dim3(8, 8, 16), 256, 0, stream>>>(amx, Wb, wb, adj, adjmix);
    rg_kernel<<<2048, 256, 0, stream>>>(rr, gc1_w, rg);
    gemm_h1<<<dim3(1, 8, 16), 256, 0, stream>>>(adjmix, rg, gc1_b, h1);
    h1g_kernel<<<320, 256, 0, stream>>>(h1, gc2_w, h1g);
    osp_kernel<<<dim3(1, 32, 16), 256, 0, stream>>>(adjmix, h1g, gc2_b, osp);
    out_kernel<<<256, 256, 0, stream>>>(osp, lh, out_w, out_b, (float*)d_out);
}

// Round 3
// 312.605 us; speedup vs baseline: 1.3848x; 1.3848x over previous
//
#include <hip/hip_runtime.h>
#include <hip/hip_bf16.h>

// dims: B=16 W=32 M=512 NH=64 HALF=32 K=8 H=8 LK=16 LOUT=2 NSP=10 GCIN=24
// rows = B*M = 8192.  All reference dtypes fp32; bf16 used internally for MFMA.

typedef __attribute__((ext_vector_type(8))) short bf16x8;
typedef __attribute__((ext_vector_type(4))) float f32x4;
#define MFMA16 __builtin_amdgcn_mfma_f32_16x16x32_bf16

__device__ __forceinline__ unsigned short f2bf(float f) {
    unsigned u = __float_as_uint(f);
    u += 0x7fff + ((u >> 16) & 1);          // RNE
    return (unsigned short)(u >> 16);
}
__device__ __forceinline__ float bf2f(unsigned short h) {
    return __uint_as_float(((unsigned)h) << 16);
}

// ---------------- K0: WbT[n][k] bf16 = Wb[k][n] ---------------------------
__global__ __launch_bounds__(256) void wbt_kernel(
    const float* __restrict__ Wb, unsigned short* __restrict__ WbT)
{
    __shared__ float tile[32][33];
    int k0 = blockIdx.y * 32, n0 = blockIdx.x * 32;
    int t = threadIdx.x;
    for (int u = t; u < 1024; u += 256) {
        int r = u >> 5, c = u & 31;
        tile[r][c] = Wb[(k0 + r) * 512 + n0 + c];
    }
    __syncthreads();
    for (int u = t; u < 1024; u += 256) {
        int r = u >> 5, c = u & 31;      // r = local n, c = local k
        WbT[(n0 + r) * 512 + k0 + c] = f2bf(tile[c][r]);
    }
}

// ---------------- K1: RNN (readlane) --------------------------------------
__global__ __launch_bounds__(256) void rnn_kernel(
    const float* __restrict__ x, const float* __restrict__ Wih,
    const float* __restrict__ Whh, const float* __restrict__ bih,
    const float* __restrict__ bhh, float* __restrict__ lh)
{
    int wid  = threadIdx.x >> 6;
    int lane = threadIdx.x & 63;
    int row  = blockIdx.x * 4 + wid;
    int b    = row >> 9;
    int m    = row & 511;

    float whh[64];
#pragma unroll
    for (int k = 0; k < 64; ++k) whh[k] = Whh[lane * 64 + k];
    float wih = Wih[lane];
    float bb  = bih[lane] + bhh[lane];

    __shared__ float sq[4][32];
    if (lane < 32) sq[wid][lane] = x[(b * 32 + lane) * 512 + m];
    __syncthreads();

    float h = 0.f;
    for (int t = 0; t < 32; ++t) {
        float acc = sq[wid][t] * wih + bb;
#pragma unroll
        for (int k = 0; k < 64; ++k) {
            float hk = __uint_as_float(
                __builtin_amdgcn_readlane(__float_as_uint(h), k));
            acc += hk * whh[k];
        }
        h = tanhf(acc);
    }
    lh[row * 64 + lane] = h;
}

// ---------------- K2: e1 = lh@W1^T, e2 = lh@W2^T --------------------------
__global__ __launch_bounds__(256) void e_kernel(
    const float* __restrict__ lh, const float* __restrict__ W1,
    const float* __restrict__ W2, float* __restrict__ e1, float* __restrict__ e2)
{
    int wid  = threadIdx.x >> 6;
    int lane = threadIdx.x & 63;
    int row  = blockIdx.x * 4 + wid;
    int hh   = lane & 31;
    const float* Wm = (lane < 32) ? W1 : W2;
    const float* hr = lh + row * 64;
    float acc = 0.f;
#pragma unroll
    for (int n = 0; n < 64; ++n) acc += hr[n] * Wm[hh * 64 + n];
    float* dst = (lane < 32) ? e1 : e2;
    dst[row * 32 + hh] = acc;
}

// ---------------- K3: a_mx, 2x2 per thread, fast elu ----------------------
__global__ __launch_bounds__(256) void amx_kernel(
    const float* __restrict__ e1, const float* __restrict__ e2,
    const float* __restrict__ b1p, const float* __restrict__ Vp,
    const float* __restrict__ bvp, float* __restrict__ amx)
{
    int bb = blockIdx.z;
    int i0 = blockIdx.y * 32, j0 = blockIdx.x * 32;
    __shared__ float e2s[32][40], e1s[32][40];
    __shared__ float Vs[32];
    int t = threadIdx.x;
    for (int u = t; u < 1024; u += 256) {
        int r = u >> 5, c = u & 31;
        e2s[r][c] = e2[(bb * 512 + i0 + r) * 32 + c];
        e1s[r][c] = e1[(bb * 512 + j0 + r) * 32 + c] + b1p[c];
    }
    if (t < 32) Vs[t] = Vp[t];
    __syncthreads();
    int ti = (t >> 4) * 2, tj = (t & 15) * 2;
    float a00 = 0, a01 = 0, a10 = 0, a11 = 0;
#define ELUF(v) ((v) > 0.f ? (v) : (__expf(v) - 1.f))
#pragma unroll
    for (int h = 0; h < 32; ++h) {
        float xi0 = e2s[ti][h], xi1 = e2s[ti + 1][h];
        float yj0 = e1s[tj][h], yj1 = e1s[tj + 1][h];
        float vv = Vs[h];
        a00 += vv * ELUF(xi0 + yj0);
        a01 += vv * ELUF(xi0 + yj1);
        a10 += vv * ELUF(xi1 + yj0);
        a11 += vv * ELUF(xi1 + yj1);
    }
    float bv = bvp[0];
    int i = bb * 512 + i0 + ti;
    float2 r0 = make_float2(a00 + bv, a01 + bv);
    float2 r1 = make_float2(a10 + bv, a11 + bv);
    *(float2*)(amx + i * 512 + j0 + tj)         = r0;
    *(float2*)(amx + (i + 1) * 512 + j0 + tj)   = r1;
}

// ---------------- K4: column norms (256 blocks) ---------------------------
__global__ __launch_bounds__(256) void norm_kernel(
    const float* __restrict__ amx, float* __restrict__ nrm)
{
    int bb = blockIdx.y, jg = blockIdx.x;
    int jj = threadIdx.x & 31, ig = threadIdx.x >> 5;
    const float* base = amx + bb * 262144 + jg * 32 + jj;
    float s = 0.f;
    for (int i = ig; i < 512; i += 8) { float v = base[i * 512]; s += v * v; }
    __shared__ float red[8][33];
    red[ig][jj] = s;
    __syncthreads();
    if (threadIdx.x < 32) {
        float tt = 0.f;
#pragma unroll
        for (int g = 0; g < 8; ++g) tt += red[g][threadIdx.x];
        nrm[bb * 512 + jg * 32 + threadIdx.x] = fmaxf(sqrtf(tt), 1e-12f);
    }
}

// ---------------- K5: scale + convert to bf16 -----------------------------
__global__ __launch_bounds__(256) void scale_kernel(
    const float* __restrict__ amx, const float* __restrict__ nrm,
    unsigned short* __restrict__ amxb)
{
    int idx = (blockIdx.x * 256 + threadIdx.x) * 4;
    int bb = idx >> 18;
    int j  = idx & 511;
    float4 v = *(const float4*)(amx + idx);
    const float* np = nrm + bb * 512 + j;
    ushort4 o;
    o.x = f2bf(v.x / np[0]); o.y = f2bf(v.y / np[1]);
    o.z = f2bf(v.z / np[2]); o.w = f2bf(v.w / np[3]);
    *(ushort4*)(amxb + idx) = o;
}

// ---------------- K6: MFMA gemm: c=sigmoid(amx_s@Wb+wb); adjmix mix -------
__global__ __launch_bounds__(256) void gemm_adjmix(
    const unsigned short* __restrict__ amxb, const unsigned short* __restrict__ WbT,
    const float* __restrict__ wbp, const float* __restrict__ adj,
    unsigned short* __restrict__ adjmix)
{
    int bb = blockIdx.z;
    int i0 = blockIdx.y * 64, j0 = blockIdx.x * 64;
    __shared__ __align__(16) short As[64 * 72];
    __shared__ __align__(16) short Bs[64 * 72];
    int t = threadIdx.x, w = t >> 6, lane = t & 63;
    int l15 = lane & 15, quad = lane >> 4;
    const unsigned short* Ag = amxb + bb * 262144;
    f32x4 acc[4] = {};
    for (int k0 = 0; k0 < 512; k0 += 64) {
        __syncthreads();
#pragma unroll
        for (int u0 = 0; u0 < 2; ++u0) {
            int u = t + u0 * 256;
            int i = u >> 3, o = u & 7;
            *(int4*)(As + i * 72 + o * 8) =
                *(const int4*)(Ag + (i0 + i) * 512 + k0 + o * 8);
            *(int4*)(Bs + i * 72 + o * 8) =
                *(const int4*)(WbT + (j0 + i) * 512 + k0 + o * 8);
        }
        __syncthreads();
        bf16x8 a0 = *(bf16x8*)(As + (16 * w + l15) * 72 + quad * 8);
        bf16x8 a1 = *(bf16x8*)(As + (16 * w + l15) * 72 + 32 + quad * 8);
#pragma unroll
        for (int nt = 0; nt < 4; ++nt) {
            bf16x8 b0 = *(bf16x8*)(Bs + (16 * nt + l15) * 72 + quad * 8);
            bf16x8 b1 = *(bf16x8*)(Bs + (16 * nt + l15) * 72 + 32 + quad * 8);
            acc[nt] = MFMA16(a0, b0, acc[nt], 0, 0, 0);
            acc[nt] = MFMA16(a1, b1, acc[nt], 0, 0, 0);
        }
    }
    float wb = wbp[0];
#pragma unroll
    for (int nt = 0; nt < 4; ++nt)
#pragma unroll
    for (int r = 0; r < 4; ++r) {
        int i = i0 + 16 * w + quad * 4 + r;
        int j = j0 + 16 * nt + l15;
        float s  = acc[nt][r] + wb;
        float cv = 1.f / (1.f + __expf(-s));
        float am = bf2f(Ag[i * 512 + j]);
        float ad = adj[i * 512 + j];
        adjmix[(bb * 512 + i) * 512 + j] = f2bf(ad * cv + am * (1.f - cv));
    }
}

// ---------------- K7: conv features r -------------------------------------
__global__ void r_kernel(
    const float* __restrict__ x, const float* __restrict__ conv_w,
    const float* __restrict__ conv_b, const float* __restrict__ convl_w,
    const float* __restrict__ convl_b, float* __restrict__ rr)
{
    int idx = blockIdx.x * 256 + threadIdx.x;
    int k   = idx & 7;
    int row = idx >> 3;
    int bb  = row >> 9, m = row & 511;
    const float* xb = x + bb * 32 * 512 + m;
    float s = conv_b[k];
    for (int w = 0; w < 32; ++w) s += xb[w * 512] * conv_w[k * 32 + w];
    float l0 = convl_b[k], l1 = l0;
    for (int tt = 0; tt < 16; ++tt) {
        float wv = convl_w[k * 16 + tt];
        l0 += xb[(2 * tt) * 512] * wv;
        l1 += xb[(2 * tt + 1) * 512] * wv;
    }
    float* dst = rr + row * 24 + k * 3;
    dst[0] = fmaxf(s, 0.f);
    dst[1] = fmaxf(l0, 0.f);
    dst[2] = fmaxf(l1, 0.f);
}

// ---------------- K8: rgT[b][n][m] bf16 = (r @ gc1_w)^T -------------------
__global__ void rg_kernel(const float* __restrict__ rr,
                          const float* __restrict__ gc1_w,
                          unsigned short* __restrict__ rgT)
{
    int idx = blockIdx.x * 256 + threadIdx.x;   // b*32768 + n*512 + m
    int m  = idx & 511;
    int n  = (idx >> 9) & 63;
    int bb = idx >> 15;
    const float* r = rr + (bb * 512 + m) * 24;
    float acc = 0.f;
#pragma unroll
    for (int c = 0; c < 24; ++c) acc += r[c] * gc1_w[c * 64 + n];
    rgT[idx] = f2bf(acc);
}

// ---------------- K9: MFMA gemm: h1 = relu(adjmix @ rg + gc1_b) -----------
__global__ __launch_bounds__(256) void gemm_h1(
    const unsigned short* __restrict__ adjmix, const unsigned short* __restrict__ rgT,
    const float* __restrict__ gc1_b, float* __restrict__ h1)
{
    int bb = blockIdx.y;
    int i0 = blockIdx.x * 32;
    __shared__ __align__(16) short As[32 * 72];
    __shared__ __align__(16) short Bs[64 * 72];
    int t = threadIdx.x, w = t >> 6, lane = t & 63;
    int l15 = lane & 15, quad = lane >> 4;
    int rt = w & 1, ntb = (w >> 1) * 2;
    const unsigned short* Ag = adjmix + bb * 262144;
    const unsigned short* Bg = rgT + bb * 32768;
    f32x4 acc[2] = {};
    for (int k0 = 0; k0 < 512; k0 += 64) {
        __syncthreads();
        {
            int i = t >> 3, o = t & 7;
            *(int4*)(As + i * 72 + o * 8) =
                *(const int4*)(Ag + (i0 + i) * 512 + k0 + o * 8);
        }
#pragma unroll
        for (int u0 = 0; u0 < 2; ++u0) {
            int u = t + u0 * 256;
            int i = u >> 3, o = u & 7;
            *(int4*)(Bs + i * 72 + o * 8) =
                *(const int4*)(Bg + i * 512 + k0 + o * 8);
        }
        __syncthreads();
        bf16x8 a0 = *(bf16x8*)(As + (16 * rt + l15) * 72 + quad * 8);
        bf16x8 a1 = *(bf16x8*)(As + (16 * rt + l15) * 72 + 32 + quad * 8);
#pragma unroll
        for (int q = 0; q < 2; ++q) {
            int nt = ntb + q;
            bf16x8 b0 = *(bf16x8*)(Bs + (16 * nt + l15) * 72 + quad * 8);
            bf16x8 b1 = *(bf16x8*)(Bs + (16 * nt + l15) * 72 + 32 + quad * 8);
            acc[q] = MFMA16(a0, b0, acc[q], 0, 0, 0);
            acc[q] = MFMA16(a1, b1, acc[q], 0, 0, 0);
        }
    }
#pragma unroll
    for (int q = 0; q < 2; ++q)
#pragma unroll
    for (int r = 0; r < 4; ++r) {
        int i = i0 + 16 * rt + quad * 4 + r;
        int j = 16 * (ntb + q) + l15;
        h1[(bb * 512 + i) * 64 + j] = fmaxf(acc[q][r] + gc1_b[j], 0.f);
    }
}

// ---------------- K10: h1g = h1 @ gc2_w -----------------------------------
__global__ void h1g_kernel(const float* __restrict__ h1,
                           const float* __restrict__ gc2_w, float* __restrict__ h1g)
{
    int idx = blockIdx.x * 256 + threadIdx.x;   // row*10 + ns
    int row = idx / 10;
    int ns  = idx - row * 10;
    const float* hr = h1 + row * 64;
    float acc = 0.f;
#pragma unroll
    for (int n = 0; n < 64; ++n) acc += hr[n] * gc2_w[n * 10 + ns];
    h1g[idx] = acc;
}

// ---------------- K11: osp = relu(adjmix @ h1g + gc2_b), wave/row ---------
__global__ __launch_bounds__(256) void osp_kernel(
    const unsigned short* __restrict__ adjmix, const float* __restrict__ h1g,
    const float* __restrict__ gc2_b, float* __restrict__ osp)
{
    int row0 = blockIdx.x * 4;                 // 4 rows/block, same batch
    int bb = row0 >> 9;
    int w = threadIdx.x >> 6, lane = threadIdx.x & 63;
    __shared__ float Bsm[10][512];
    for (int u = threadIdx.x; u < 5120; u += 256) {
        int k = u / 10, ns = u - k * 10;
        Bsm[ns][k] = h1g[bb * 5120 + u];
    }
    __syncthreads();
    int row = row0 + w;
    const unsigned short* Ar = adjmix + row * 512;
    float a[8];
#pragma unroll
    for (int q = 0; q < 8; ++q) a[q] = bf2f(Ar[lane + 64 * q]);
#pragma unroll
    for (int ns = 0; ns < 10; ++ns) {
        float s = 0.f;
#pragma unroll
        for (int q = 0; q < 8; ++q) s += a[q] * Bsm[ns][lane + 64 * q];
        for (int off = 32; off; off >>= 1) s += __shfl_down(s, off);
        if (lane == 0) osp[row * 10 + ns] = fmaxf(s + gc2_b[ns], 0.f);
    }
}

// ---------------- K12: out ------------------------------------------------
__global__ void out_kernel(
    const float* __restrict__ osp, const float* __restrict__ lh,
    const float* __restrict__ out_w, const float* __restrict__ out_b,
    float* __restrict__ out)
{
    int idx = blockIdx.x * 256 + threadIdx.x;
    int m  = idx & 511;
    int hh = (idx >> 9) & 7;
    int bb = idx >> 12;
    const float* of = osp + (bb * 512 + m) * 10;
    const float* lf = lh + (bb * 512 + m) * 64;
    float acc = out_b[hh];
#pragma unroll
    for (int n = 0; n < 10; ++n) acc += of[n] * out_w[hh * 74 + n];
#pragma unroll
    for (int n = 0; n < 64; ++n) acc += lf[n] * out_w[hh * 74 + 10 + n];
    out[idx] = acc;
}

// ---------------- launch ---------------------------------------------------
extern "C" void kernel_launch(void* const* d_in, const int* in_sizes, int n_in,
                              void* d_out, int out_size, void* d_ws, size_t ws_size,
                              hipStream_t stream)
{
    const float* x       = (const float*)d_in[0];
    const float* adj     = (const float*)d_in[1];
    const float* Wih     = (const float*)d_in[2];
    const float* Whh     = (const float*)d_in[3];
    const float* bih     = (const float*)d_in[4];
    const float* bhh     = (const float*)d_in[5];
    const float* W1      = (const float*)d_in[6];
    const float* W2      = (const float*)d_in[7];
    const float* b1      = (const float*)d_in[8];
    const float* V       = (const float*)d_in[9];
    const float* bv      = (const float*)d_in[10];
    const float* Wb      = (const float*)d_in[11];
    const float* wb      = (const float*)d_in[12];
    const float* conv_w  = (const float*)d_in[13];
    const float* conv_b  = (const float*)d_in[14];
    const float* convl_w = (const float*)d_in[15];
    const float* convl_b = (const float*)d_in[16];
    const float* gc1_w   = (const float*)d_in[17];
    const float* gc1_b   = (const float*)d_in[18];
    const float* gc2_w   = (const float*)d_in[19];
    const float* gc2_b   = (const float*)d_in[20];
    const float* out_w   = (const float*)d_in[21];
    const float* out_b   = (const float*)d_in[22];

    float* ws  = (float*)d_ws;
    float* lh  = ws;                    // 524288
    float* e1  = lh + 524288;           // 262144
    float* e2  = e1 + 262144;           // 262144
    float* amx = e2 + 262144;           // 4194304
    float* nrm = amx + 4194304;         // 8192
    float* rr  = nrm + 8192;            // 196608
    float* h1  = rr + 196608;           // 524288
    float* h1g = h1 + 524288;           // 81920
    float* osp = h1g + 81920;           // 81920
    unsigned short* bfbase  = (unsigned short*)(osp + 81920);
    unsigned short* amxb    = bfbase;                 // 4194304 ushort
    unsigned short* adjmixb = amxb + 4194304;         // 4194304
    unsigned short* WbT     = adjmixb + 4194304;      // 262144
    unsigned short* rgT     = WbT + 262144;           // 524288

    wbt_kernel<<<dim3(16, 16), 256, 0, stream>>>(Wb, WbT);
    rnn_kernel<<<2048, 256, 0, stream>>>(x, Wih, Whh, bih, bhh, lh);
    r_kernel<<<256, 256, 0, stream>>>(x, conv_w, conv_b, convl_w, convl_b, rr);
    e_kernel<<<2048, 256, 0, stream>>>(lh, W1, W2, e1, e2);
    amx_kernel<<<dim3(16, 16, 16), 256, 0, stream>>>(e1, e2, b1, V, bv, amx);
    norm_kernel<<<dim3(16, 16), 256, 0, stream>>>(amx, nrm);
    scale_kernel<<<4096, 256, 0, stream>>>(amx, nrm, amxb);
    gemm_adjmix<<<dim3(8, 8, 16), 256, 0, stream>>>(amxb, WbT, wb, adj, adjmixb);
    rg_kernel<<<2048, 256, 0, stream>>>(rr, gc1_w, rgT);
    gemm_h1<<<dim3(16, 16), 256, 0, stream>>>(adjmixb, rgT, gc1_b, h1);
    h1g_kernel<<<320, 256, 0, stream>>>(h1, gc2_w, h1g);
    osp_kernel<<<2048, 256, 0, stream>>>(adjmixb, h1g, gc2_b, osp);
    out_kernel<<<256, 256, 0, stream>>>(osp, lh, out_w, out_b, (float*)d_out);
}

// Round 4
// 251.773 us; speedup vs baseline: 1.7193x; 1.2416x over previous
//
#include <hip/hip_runtime.h>
#include <hip/hip_bf16.h>

// dims: B=16 W=32 M=512 NH=64 HALF=32 K=8 H=8 LK=16 LOUT=2 NSP=10 GCIN=24
// rows = B*M = 8192.  Reference dtypes fp32; bf16 internally for MFMA.

typedef __attribute__((ext_vector_type(8))) short bf16x8;
typedef __attribute__((ext_vector_type(4))) float f32x4;
#define MFMA16 __builtin_amdgcn_mfma_f32_16x16x32_bf16

__device__ __forceinline__ unsigned short f2bf(float f) {
    unsigned u = __float_as_uint(f);
    u += 0x7fff + ((u >> 16) & 1);          // RNE
    return (unsigned short)(u >> 16);
}
__device__ __forceinline__ float bf2f(unsigned short h) {
    return __uint_as_float(((unsigned)h) << 16);
}
// fast tanh: 1 - 2/(e^{2x}+1); exp via HW v_exp; saturates correctly at +-inf
__device__ __forceinline__ float fast_tanh(float x) {
    float e = __expf(2.f * x);
    return 1.f - 2.f / (e + 1.f);
}

// ---------------- K0: WbT[n][k] bf16 = Wb[k][n] ---------------------------
__global__ __launch_bounds__(256) void wbt_kernel(
    const float* __restrict__ Wb, unsigned short* __restrict__ WbT)
{
    __shared__ float tile[32][33];
    int k0 = blockIdx.y * 32, n0 = blockIdx.x * 32;
    int t = threadIdx.x;
    for (int u = t; u < 1024; u += 256) {
        int r = u >> 5, c = u & 31;
        tile[r][c] = Wb[(k0 + r) * 512 + n0 + c];
    }
    __syncthreads();
    for (int u = t; u < 1024; u += 256) {
        int r = u >> 5, c = u & 31;
        WbT[(n0 + r) * 512 + k0 + c] = f2bf(tile[c][r]);
    }
}

// ---------------- K1: RNN via MFMA ----------------------------------------
// 1 wave / 16 rows. O^T = Whh * h^T: A = Whh (static, VGPR-resident),
// B = h^T read as h[l15][quad*8+j] (b128), D cols land contiguous -> b64 write.
__global__ __launch_bounds__(64) void rnn_kernel(
    const float* __restrict__ x, const float* __restrict__ Wih,
    const float* __restrict__ Whh, const float* __restrict__ bih,
    const float* __restrict__ bhh, float* __restrict__ lhT)
{
    int lane = threadIdx.x;
    int l15 = lane & 15, quad = lane >> 4;
    int row0 = blockIdx.x * 16;
    int b = row0 >> 9, m0 = row0 & 511;

    // A-fragments: afr[mt][hf] = Whh[16mt+l15][32hf + quad*8 .. +7]
    bf16x8 afr[4][2];
#pragma unroll
    for (int mt = 0; mt < 4; ++mt)
#pragma unroll
        for (int hf = 0; hf < 2; ++hf) {
            const float* src = Whh + (16 * mt + l15) * 64 + 32 * hf + quad * 8;
            union { bf16x8 v; unsigned short u[8]; } tmp;
#pragma unroll
            for (int j = 0; j < 8; ++j) tmp.u[j] = f2bf(src[j]);
            afr[mt][hf] = tmp.v;
        }
    // per-lane n = 16mt + quad*4 + r
    float wihv[4][4], bsv[4][4];
#pragma unroll
    for (int mt = 0; mt < 4; ++mt)
#pragma unroll
        for (int r = 0; r < 4; ++r) {
            int n = 16 * mt + quad * 4 + r;
            wihv[mt][r] = Wih[n];
            bsv[mt][r]  = bih[n] + bhh[n];
        }

    __shared__ float xs[32][16];
    __shared__ __align__(16) unsigned short hs[16][72];
    for (int u = lane; u < 512; u += 64) {
        int t = u >> 4, mm = u & 15;
        xs[t][mm] = x[(b * 32 + t) * 512 + m0 + mm];
    }
    for (int u = lane; u < 16 * 72; u += 64) ((unsigned short*)hs)[u] = 0;
    __syncthreads();

    for (int t = 0; t < 32; ++t) {
        bf16x8 b0 = *(bf16x8*)(&hs[l15][quad * 8]);
        bf16x8 b1 = *(bf16x8*)(&hs[l15][32 + quad * 8]);
        float xt = xs[t][l15];
        f32x4 acc[4];
#pragma unroll
        for (int mt = 0; mt < 4; ++mt) {
            f32x4 z = {0.f, 0.f, 0.f, 0.f};
            acc[mt] = MFMA16(afr[mt][0], b0, z, 0, 0, 0);
            acc[mt] = MFMA16(afr[mt][1], b1, acc[mt], 0, 0, 0);
        }
#pragma unroll
        for (int mt = 0; mt < 4; ++mt) {
            ushort4 hw;
            float th[4];
#pragma unroll
            for (int r = 0; r < 4; ++r) {
                float v = acc[mt][r] + xt * wihv[mt][r] + bsv[mt][r];
                th[r] = fast_tanh(v);
            }
            hw.x = f2bf(th[0]); hw.y = f2bf(th[1]);
            hw.z = f2bf(th[2]); hw.w = f2bf(th[3]);
            *(ushort4*)(&hs[l15][16 * mt + quad * 4]) = hw;
            if (t == 31) {
#pragma unroll
                for (int r = 0; r < 4; ++r) {
                    int n = 16 * mt + quad * 4 + r;
                    lhT[n * 8192 + row0 + l15] = th[r];
                }
            }
        }
    }
}

// ---------------- K2: e1 = lh@W1^T, e2 = lh@W2^T (lhT layout) -------------
__global__ __launch_bounds__(256) void e_kernel(
    const float* __restrict__ lhT, const float* __restrict__ W1,
    const float* __restrict__ W2, float* __restrict__ e1, float* __restrict__ e2)
{
    int wid  = threadIdx.x >> 6;
    int lane = threadIdx.x & 63;
    int row  = blockIdx.x * 4 + wid;
    int hh   = lane & 31;
    const float* Wm = (lane < 32) ? W1 : W2;
    float acc = 0.f;
#pragma unroll
    for (int n = 0; n < 64; ++n) acc += lhT[n * 8192 + row] * Wm[hh * 64 + n];
    float* dst = (lane < 32) ? e1 : e2;
    dst[row * 32 + hh] = acc;
}

// ---------------- K3: a_mx 4x4/thread + fused column sumsq ----------------
__global__ __launch_bounds__(256) void amx_kernel(
    const float* __restrict__ e1, const float* __restrict__ e2,
    const float* __restrict__ b1p, const float* __restrict__ Vp,
    const float* __restrict__ bvp, float* __restrict__ amx,
    float* __restrict__ nrmss)
{
    int bb = blockIdx.z;
    int i0 = blockIdx.y * 64, j0 = blockIdx.x * 64;
    __shared__ float e2s[64][33], e1s[64][33];
    __shared__ float Vs[32];
    __shared__ float red[16][68];
    int t = threadIdx.x;
    for (int u = t; u < 2048; u += 256) {
        int r = u >> 5, c = u & 31;
        e2s[r][c] = e2[(bb * 512 + i0 + r) * 32 + c];
        e1s[r][c] = e1[(bb * 512 + j0 + r) * 32 + c] + b1p[c];
    }
    if (t < 32) Vs[t] = Vp[t];
    __syncthreads();
    int ti = (t >> 4) * 4, tj = (t & 15) * 4;
    float acc[4][4] = {};
#define ELUF(v) ((v) > 0.f ? (v) : (__expf(v) - 1.f))
#pragma unroll
    for (int h = 0; h < 32; ++h) {
        float vv = Vs[h];
        float xi[4], yj[4];
#pragma unroll
        for (int p = 0; p < 4; ++p) xi[p] = e2s[ti + p][h];
#pragma unroll
        for (int q = 0; q < 4; ++q) yj[q] = e1s[tj + q][h];
#pragma unroll
        for (int p = 0; p < 4; ++p)
#pragma unroll
            for (int q = 0; q < 4; ++q)
                acc[p][q] += vv * ELUF(xi[p] + yj[q]);
    }
    float bv = bvp[0];
    float ss[4] = {0.f, 0.f, 0.f, 0.f};
#pragma unroll
    for (int p = 0; p < 4; ++p) {
        float4 o;
        o.x = acc[p][0] + bv; o.y = acc[p][1] + bv;
        o.z = acc[p][2] + bv; o.w = acc[p][3] + bv;
        *(float4*)(amx + (bb * 512 + i0 + ti + p) * 512 + j0 + tj) = o;
        ss[0] += o.x * o.x; ss[1] += o.y * o.y;
        ss[2] += o.z * o.z; ss[3] += o.w * o.w;
    }
#pragma unroll
    for (int q = 0; q < 4; ++q) red[t >> 4][tj + q] = ss[q];
    __syncthreads();
    if (t < 64) {
        float s = 0.f;
#pragma unroll
        for (int g = 0; g < 16; ++g) s += red[g][t];
        atomicAdd(&nrmss[bb * 512 + j0 + t], s);
    }
}

// ---------------- K4: nrm -> reciprocal norm ------------------------------
__global__ void normfin_kernel(float* __restrict__ nrm)
{
    int j = blockIdx.x * 256 + threadIdx.x;
    nrm[j] = 1.f / fmaxf(sqrtf(nrm[j]), 1e-12f);
}

// ---------------- K5: scale (multiply by recip) + convert to bf16 ---------
__global__ __launch_bounds__(256) void scale_kernel(
    const float* __restrict__ amx, const float* __restrict__ nrm,
    unsigned short* __restrict__ amxb)
{
    int idx = (blockIdx.x * 256 + threadIdx.x) * 4;
    int bb = idx >> 18;
    int j  = idx & 511;
    float4 v = *(const float4*)(amx + idx);
    const float* np = nrm + bb * 512 + j;
    ushort4 o;
    o.x = f2bf(v.x * np[0]); o.y = f2bf(v.y * np[1]);
    o.z = f2bf(v.z * np[2]); o.w = f2bf(v.w * np[3]);
    *(ushort4*)(amxb + idx) = o;
}

// ---------------- K6: MFMA gemm: c=sigmoid(amx_s@Wb+wb); adjmix mix -------
__global__ __launch_bounds__(256) void gemm_adjmix(
    const unsigned short* __restrict__ amxb, const unsigned short* __restrict__ WbT,
    const float* __restrict__ wbp, const float* __restrict__ adj,
    unsigned short* __restrict__ adjmix)
{
    int bb = blockIdx.z;
    int i0 = blockIdx.y * 64, j0 = blockIdx.x * 64;
    __shared__ __align__(16) short As[64 * 72];
    __shared__ __align__(16) short Bs[64 * 72];
    int t = threadIdx.x, w = t >> 6, lane = t & 63;
    int l15 = lane & 15, quad = lane >> 4;
    const unsigned short* Ag = amxb + bb * 262144;
    f32x4 acc[4] = {};
    for (int k0 = 0; k0 < 512; k0 += 64) {
        __syncthreads();
#pragma unroll
        for (int u0 = 0; u0 < 2; ++u0) {
            int u = t + u0 * 256;
            int i = u >> 3, o = u & 7;
            *(int4*)(As + i * 72 + o * 8) =
                *(const int4*)(Ag + (i0 + i) * 512 + k0 + o * 8);
            *(int4*)(Bs + i * 72 + o * 8) =
                *(const int4*)(WbT + (j0 + i) * 512 + k0 + o * 8);
        }
        __syncthreads();
        bf16x8 a0 = *(bf16x8*)(As + (16 * w + l15) * 72 + quad * 8);
        bf16x8 a1 = *(bf16x8*)(As + (16 * w + l15) * 72 + 32 + quad * 8);
#pragma unroll
        for (int nt = 0; nt < 4; ++nt) {
            bf16x8 b0 = *(bf16x8*)(Bs + (16 * nt + l15) * 72 + quad * 8);
            bf16x8 b1 = *(bf16x8*)(Bs + (16 * nt + l15) * 72 + 32 + quad * 8);
            acc[nt] = MFMA16(a0, b0, acc[nt], 0, 0, 0);
            acc[nt] = MFMA16(a1, b1, acc[nt], 0, 0, 0);
        }
    }
    float wb = wbp[0];
#pragma unroll
    for (int nt = 0; nt < 4; ++nt)
#pragma unroll
    for (int r = 0; r < 4; ++r) {
        int i = i0 + 16 * w + quad * 4 + r;
        int j = j0 + 16 * nt + l15;
        float s  = acc[nt][r] + wb;
        float cv = 1.f / (1.f + __expf(-s));
        float am = bf2f(Ag[i * 512 + j]);
        float ad = adj[i * 512 + j];
        adjmix[(bb * 512 + i) * 512 + j] = f2bf(ad * cv + am * (1.f - cv));
    }
}

// ---------------- K7: conv features r -------------------------------------
__global__ void r_kernel(
    const float* __restrict__ x, const float* __restrict__ conv_w,
    const float* __restrict__ conv_b, const float* __restrict__ convl_w,
    const float* __restrict__ convl_b, float* __restrict__ rr)
{
    int idx = blockIdx.x * 256 + threadIdx.x;
    int k   = idx & 7;
    int row = idx >> 3;
    int bb  = row >> 9, m = row & 511;
    const float* xb = x + bb * 32 * 512 + m;
    float s = conv_b[k];
    for (int w = 0; w < 32; ++w) s += xb[w * 512] * conv_w[k * 32 + w];
    float l0 = convl_b[k], l1 = l0;
    for (int tt = 0; tt < 16; ++tt) {
        float wv = convl_w[k * 16 + tt];
        l0 += xb[(2 * tt) * 512] * wv;
        l1 += xb[(2 * tt + 1) * 512] * wv;
    }
    float* dst = rr + row * 24 + k * 3;
    dst[0] = fmaxf(s, 0.f);
    dst[1] = fmaxf(l0, 0.f);
    dst[2] = fmaxf(l1, 0.f);
}

// ---------------- K8: rgT[b][n][m] bf16 = (r @ gc1_w)^T -------------------
__global__ void rg_kernel(const float* __restrict__ rr,
                          const float* __restrict__ gc1_w,
                          unsigned short* __restrict__ rgT)
{
    int idx = blockIdx.x * 256 + threadIdx.x;
    int m  = idx & 511;
    int n  = (idx >> 9) & 63;
    int bb = idx >> 15;
    const float* r = rr + (bb * 512 + m) * 24;
    float acc = 0.f;
#pragma unroll
    for (int c = 0; c < 24; ++c) acc += r[c] * gc1_w[c * 64 + n];
    rgT[idx] = f2bf(acc);
}

// ---------------- K9: MFMA gemm: h1 = relu(adjmix @ rg + gc1_b) -----------
__global__ __launch_bounds__(256) void gemm_h1(
    const unsigned short* __restrict__ adjmix, const unsigned short* __restrict__ rgT,
    const float* __restrict__ gc1_b, float* __restrict__ h1)
{
    int bb = blockIdx.y;
    int i0 = blockIdx.x * 32;
    __shared__ __align__(16) short As[32 * 72];
    __shared__ __align__(16) short Bs[64 * 72];
    int t = threadIdx.x, w = t >> 6, lane = t & 63;
    int l15 = lane & 15, quad = lane >> 4;
    int rt = w & 1, ntb = (w >> 1) * 2;
    const unsigned short* Ag = adjmix + bb * 262144;
    const unsigned short* Bg = rgT + bb * 32768;
    f32x4 acc[2] = {};
    for (int k0 = 0; k0 < 512; k0 += 64) {
        __syncthreads();
        {
            int i = t >> 3, o = t & 7;
            *(int4*)(As + i * 72 + o * 8) =
                *(const int4*)(Ag + (i0 + i) * 512 + k0 + o * 8);
        }
#pragma unroll
        for (int u0 = 0; u0 < 2; ++u0) {
            int u = t + u0 * 256;
            int i = u >> 3, o = u & 7;
            *(int4*)(Bs + i * 72 + o * 8) =
                *(const int4*)(Bg + i * 512 + k0 + o * 8);
        }
        __syncthreads();
        bf16x8 a0 = *(bf16x8*)(As + (16 * rt + l15) * 72 + quad * 8);
        bf16x8 a1 = *(bf16x8*)(As + (16 * rt + l15) * 72 + 32 + quad * 8);
#pragma unroll
        for (int q = 0; q < 2; ++q) {
            int nt = ntb + q;
            bf16x8 b0 = *(bf16x8*)(Bs + (16 * nt + l15) * 72 + quad * 8);
            bf16x8 b1 = *(bf16x8*)(Bs + (16 * nt + l15) * 72 + 32 + quad * 8);
            acc[q] = MFMA16(a0, b0, acc[q], 0, 0, 0);
            acc[q] = MFMA16(a1, b1, acc[q], 0, 0, 0);
        }
    }
#pragma unroll
    for (int q = 0; q < 2; ++q)
#pragma unroll
    for (int r = 0; r < 4; ++r) {
        int i = i0 + 16 * rt + quad * 4 + r;
        int j = 16 * (ntb + q) + l15;
        h1[(bb * 512 + i) * 64 + j] = fmaxf(acc[q][r] + gc1_b[j], 0.f);
    }
}

// ---------------- K10: h1g = h1 @ gc2_w -----------------------------------
__global__ void h1g_kernel(const float* __restrict__ h1,
                           const float* __restrict__ gc2_w, float* __restrict__ h1g)
{
    int idx = blockIdx.x * 256 + threadIdx.x;
    int row = idx / 10;
    int ns  = idx - row * 10;
    const float* hr = h1 + row * 64;
    float acc = 0.f;
#pragma unroll
    for (int n = 0; n < 64; ++n) acc += hr[n] * gc2_w[n * 10 + ns];
    h1g[idx] = acc;
}

// ---------------- K11: osp = relu(adjmix @ h1g + gc2_b), wave/row ---------
__global__ __launch_bounds__(256) void osp_kernel(
    const unsigned short* __restrict__ adjmix, const float* __restrict__ h1g,
    const float* __restrict__ gc2_b, float* __restrict__ osp)
{
    int row0 = blockIdx.x * 4;
    int bb = row0 >> 9;
    int w = threadIdx.x >> 6, lane = threadIdx.x & 63;
    __shared__ float Bsm[10][512];
    for (int u = threadIdx.x; u < 5120; u += 256) {
        int k = u / 10, ns = u - k * 10;
        Bsm[ns][k] = h1g[bb * 5120 + u];
    }
    __syncthreads();
    int row = row0 + w;
    const unsigned short* Ar = adjmix + row * 512;
    float a[8];
#pragma unroll
    for (int q = 0; q < 8; ++q) a[q] = bf2f(Ar[lane + 64 * q]);
#pragma unroll
    for (int ns = 0; ns < 10; ++ns) {
        float s = 0.f;
#pragma unroll
        for (int q = 0; q < 8; ++q) s += a[q] * Bsm[ns][lane + 64 * q];
        for (int off = 32; off; off >>= 1) s += __shfl_down(s, off);
        if (lane == 0) osp[row * 10 + ns] = fmaxf(s + gc2_b[ns], 0.f);
    }
}

// ---------------- K12: out (lhT layout -> coalesced) ----------------------
__global__ void out_kernel(
    const float* __restrict__ osp, const float* __restrict__ lhT,
    const float* __restrict__ out_w, const float* __restrict__ out_b,
    float* __restrict__ out)
{
    int idx = blockIdx.x * 256 + threadIdx.x;
    int m  = idx & 511;
    int hh = (idx >> 9) & 7;
    int bb = idx >> 12;
    const float* of = osp + (bb * 512 + m) * 10;
    float acc = out_b[hh];
#pragma unroll
    for (int n = 0; n < 10; ++n) acc += of[n] * out_w[hh * 74 + n];
#pragma unroll
    for (int n = 0; n < 64; ++n)
        acc += lhT[n * 8192 + bb * 512 + m] * out_w[hh * 74 + 10 + n];
    out[idx] = acc;
}

// ---------------- launch ---------------------------------------------------
extern "C" void kernel_launch(void* const* d_in, const int* in_sizes, int n_in,
                              void* d_out, int out_size, void* d_ws, size_t ws_size,
                              hipStream_t stream)
{
    const float* x       = (const float*)d_in[0];
    const float* adj     = (const float*)d_in[1];
    const float* Wih     = (const float*)d_in[2];
    const float* Whh     = (const float*)d_in[3];
    const float* bih     = (const float*)d_in[4];
    const float* bhh     = (const float*)d_in[5];
    const float* W1      = (const float*)d_in[6];
    const float* W2      = (const float*)d_in[7];
    const float* b1      = (const float*)d_in[8];
    const float* V       = (const float*)d_in[9];
    const float* bv      = (const float*)d_in[10];
    const float* Wb      = (const float*)d_in[11];
    const float* wb      = (const float*)d_in[12];
    const float* conv_w  = (const float*)d_in[13];
    const float* conv_b  = (const float*)d_in[14];
    const float* convl_w = (const float*)d_in[15];
    const float* convl_b = (const float*)d_in[16];
    const float* gc1_w   = (const float*)d_in[17];
    const float* gc1_b   = (const float*)d_in[18];
    const float* gc2_w   = (const float*)d_in[19];
    const float* gc2_b   = (const float*)d_in[20];
    const float* out_w   = (const float*)d_in[21];
    const float* out_b   = (const float*)d_in[22];

    float* ws   = (float*)d_ws;
    float* lhT  = ws;                   // 524288
    float* e1   = lhT + 524288;         // 262144
    float* e2   = e1 + 262144;          // 262144
    float* amx  = e2 + 262144;          // 4194304
    float* nrm  = amx + 4194304;        // 8192
    float* rr   = nrm + 8192;           // 196608
    float* h1   = rr + 196608;          // 524288
    float* h1g  = h1 + 524288;          // 81920
    float* osp  = h1g + 81920;          // 81920
    unsigned short* bfbase  = (unsigned short*)(osp + 81920);
    unsigned short* amxb    = bfbase;                 // 4194304 ushort
    unsigned short* adjmixb = amxb + 4194304;         // 4194304
    unsigned short* WbT     = adjmixb + 4194304;      // 262144
    unsigned short* rgT     = WbT + 262144;           // 524288

    hipMemsetAsync(nrm, 0, 8192 * sizeof(float), stream);
    wbt_kernel<<<dim3(16, 16), 256, 0, stream>>>(Wb, WbT);
    rnn_kernel<<<512, 64, 0, stream>>>(x, Wih, Whh, bih, bhh, lhT);
    r_kernel<<<256, 256, 0, stream>>>(x, conv_w, conv_b, convl_w, convl_b, rr);
    e_kernel<<<2048, 256, 0, stream>>>(lhT, W1, W2, e1, e2);
    amx_kernel<<<dim3(8, 8, 16), 256, 0, stream>>>(e1, e2, b1, V, bv, amx, nrm);
    normfin_kernel<<<32, 256, 0, stream>>>(nrm);
    scale_kernel<<<4096, 256, 0, stream>>>(amx, nrm, amxb);
    gemm_adjmix<<<dim3(8, 8, 16), 256, 0, stream>>>(amxb, WbT, wb, adj, adjmixb);
    rg_kernel<<<2048, 256, 0, stream>>>(rr, gc1_w, rgT);
    gemm_h1<<<dim3(16, 16), 256, 0, stream>>>(adjmixb, rgT, gc1_b, h1);
    h1g_kernel<<<320, 256, 0, stream>>>(h1, gc2_w, h1g);
    osp_kernel<<<2048, 256, 0, stream>>>(adjmixb, h1g, gc2_b, osp);
    out_kernel<<<256, 256, 0, stream>>>(osp, lhT, out_w, out_b, (float*)d_out);
}

// Round 5
// 220.331 us; speedup vs baseline: 1.9647x; 1.1427x over previous
//
#include <hip/hip_runtime.h>

// dims: B=16 W=32 M=512 NH=64 HALF=32 K=8 H=8 LK=16 LOUT=2 NSP=10 GCIN=24
// rows = B*M = 8192. Reference dtypes fp32; bf16 internally for MFMA.
// 6 dispatches: prep, rnn(+e), amx(bf16+sumsq), gemm_adjmix(+norm), gemm_h1(+h1g), ospout.

typedef __attribute__((ext_vector_type(8))) short bf16x8;
typedef __attribute__((ext_vector_type(4))) float f32x4;
#define MFMA16 __builtin_amdgcn_mfma_f32_16x16x32_bf16

__device__ __forceinline__ unsigned short f2bf(float f) {
    unsigned u = __float_as_uint(f);
    u += 0x7fff + ((u >> 16) & 1);          // RNE
    return (unsigned short)(u >> 16);
}
__device__ __forceinline__ float bf2f(unsigned short h) {
    return __uint_as_float(((unsigned)h) << 16);
}
__device__ __forceinline__ float fast_tanh(float x) {
    float e = __expf(2.f * x);
    return 1.f - 2.f / (e + 1.f);
}

// ---------------- K1: prep = (r+rg fused) | wbt | zero nrmss --------------
__global__ __launch_bounds__(256) void prep_kernel(
    const float* __restrict__ x, const float* __restrict__ conv_w,
    const float* __restrict__ conv_b, const float* __restrict__ convl_w,
    const float* __restrict__ convl_b, const float* __restrict__ gc1_w,
    unsigned short* __restrict__ rgT,
    const float* __restrict__ Wb, unsigned short* __restrict__ WbT,
    float* __restrict__ nrmss)
{
    int blk = blockIdx.x, t = threadIdx.x;
    if (blk < 256) {
        // conv features for 32 rows -> LDS -> rgT = (relu(r) @ gc1_w)^T bf16
        int r0 = blk * 32;
        int bb = r0 >> 9, m0 = r0 & 511;
        __shared__ float rrs[32][25];
        {
            int k = t & 7, rl = t >> 3;
            const float* xb = x + bb * 16384 + m0 + rl;
            float s = conv_b[k];
            for (int w = 0; w < 32; ++w) s += xb[w * 512] * conv_w[k * 32 + w];
            float l0 = convl_b[k], l1 = l0;
            for (int tt = 0; tt < 16; ++tt) {
                float wv = convl_w[k * 16 + tt];
                l0 += xb[(2 * tt) * 512] * wv;
                l1 += xb[(2 * tt + 1) * 512] * wv;
            }
            rrs[rl][k * 3 + 0] = fmaxf(s, 0.f);
            rrs[rl][k * 3 + 1] = fmaxf(l0, 0.f);
            rrs[rl][k * 3 + 2] = fmaxf(l1, 0.f);
        }
        __syncthreads();
        int rl = t & 31, nb = t >> 5;
#pragma unroll
        for (int q = 0; q < 8; ++q) {
            int n = nb * 8 + q;
            float acc = 0.f;
#pragma unroll
            for (int c = 0; c < 24; ++c) acc += rrs[rl][c] * gc1_w[c * 64 + n];
            rgT[bb * 32768 + n * 512 + m0 + rl] = f2bf(acc);
        }
    } else if (blk < 512) {
        int bid = blk - 256;
        int nb = (bid & 15) * 32, kb = (bid >> 4) * 32;
        __shared__ float tile[32][33];
        for (int u = t; u < 1024; u += 256) {
            int r = u >> 5, c = u & 31;
            tile[r][c] = Wb[(kb + r) * 512 + nb + c];
        }
        __syncthreads();
        for (int u = t; u < 1024; u += 256) {
            int r = u >> 5, c = u & 31;
            WbT[(nb + r) * 512 + kb + c] = f2bf(tile[c][r]);
        }
    } else {
        nrmss[(blk - 512) * 256 + t] = 0.f;
    }
}

// ---------------- K2: RNN via MFMA + fused e1/e2 epilogue -----------------
// 4 waves/block, each wave owns 16 series. O^T = Whh*h^T (A=Whh in VGPRs,
// h in LDS bf16). Epilogue: e1/e2 = h @ W{1,2}^T via 4 more tile-MFMAs.
__global__ __launch_bounds__(256) void rnn_kernel(
    const float* __restrict__ x, const float* __restrict__ Wih,
    const float* __restrict__ Whh, const float* __restrict__ bih,
    const float* __restrict__ bhh, const float* __restrict__ W1,
    const float* __restrict__ W2, float* __restrict__ lh,
    float* __restrict__ e1, float* __restrict__ e2)
{
    int t = threadIdx.x, wid = t >> 6, lane = t & 63;
    int l15 = lane & 15, quad = lane >> 4;
    int rowblk = blockIdx.x * 64;
    int row0 = rowblk + wid * 16;
    int b = rowblk >> 9, mb = rowblk & 511;

    bf16x8 afr[4][2];
#pragma unroll
    for (int mt = 0; mt < 4; ++mt)
#pragma unroll
        for (int hf = 0; hf < 2; ++hf) {
            const float* src = Whh + (16 * mt + l15) * 64 + 32 * hf + quad * 8;
            union { bf16x8 v; unsigned short u[8]; } tmp;
#pragma unroll
            for (int j = 0; j < 8; ++j) tmp.u[j] = f2bf(src[j]);
            afr[mt][hf] = tmp.v;
        }
    bf16x8 wfr[2][2][2];   // [e][nt][kf]
#pragma unroll
    for (int e = 0; e < 2; ++e)
#pragma unroll
        for (int nt = 0; nt < 2; ++nt)
#pragma unroll
            for (int kf = 0; kf < 2; ++kf) {
                const float* Wsrc = (e ? W2 : W1);
                const float* src = Wsrc + (16 * nt + l15) * 64 + 32 * kf + quad * 8;
                union { bf16x8 v; unsigned short u[8]; } tmp;
#pragma unroll
                for (int j = 0; j < 8; ++j) tmp.u[j] = f2bf(src[j]);
                wfr[e][nt][kf] = tmp.v;
            }
    float wihv[4][4], bsv[4][4];
#pragma unroll
    for (int mt = 0; mt < 4; ++mt)
#pragma unroll
        for (int r = 0; r < 4; ++r) {
            int n = 16 * mt + quad * 4 + r;
            wihv[mt][r] = Wih[n];
            bsv[mt][r]  = bih[n] + bhh[n];
        }

    __shared__ float xs[32][64];
    __shared__ __align__(16) unsigned short hs[4][16][72];
    for (int u = t; u < 2048; u += 256) {
        int tt = u >> 6, c = u & 63;
        xs[tt][c] = x[(b * 32 + tt) * 512 + mb + c];
    }
    for (int u = lane; u < 16 * 72; u += 64) (&hs[wid][0][0])[u] = 0;
    __syncthreads();

    int mloc = wid * 16;
    float th[4][4];
    for (int tstep = 0; tstep < 32; ++tstep) {
        bf16x8 b0 = *(bf16x8*)(&hs[wid][l15][quad * 8]);
        bf16x8 b1 = *(bf16x8*)(&hs[wid][l15][32 + quad * 8]);
        float xt = xs[tstep][mloc + l15];
        f32x4 acc[4];
#pragma unroll
        for (int mt = 0; mt < 4; ++mt) {
            f32x4 z = {0.f, 0.f, 0.f, 0.f};
            acc[mt] = MFMA16(afr[mt][0], b0, z, 0, 0, 0);
            acc[mt] = MFMA16(afr[mt][1], b1, acc[mt], 0, 0, 0);
        }
#pragma unroll
        for (int mt = 0; mt < 4; ++mt) {
            ushort4 hw;
#pragma unroll
            for (int r = 0; r < 4; ++r)
                th[mt][r] = fast_tanh(acc[mt][r] + xt * wihv[mt][r] + bsv[mt][r]);
            hw.x = f2bf(th[mt][0]); hw.y = f2bf(th[mt][1]);
            hw.z = f2bf(th[mt][2]); hw.w = f2bf(th[mt][3]);
            *(ushort4*)(&hs[wid][l15][16 * mt + quad * 4]) = hw;
        }
    }
    // last_hid row-major (consumed coalesced by ospout)
#pragma unroll
    for (int mt = 0; mt < 4; ++mt)
        *(float4*)(lh + (row0 + l15) * 64 + 16 * mt + quad * 4) =
            make_float4(th[mt][0], th[mt][1], th[mt][2], th[mt][3]);

    // e1/e2 epilogue: A = h (rows=series), B = W{1,2} rows
    bf16x8 a0 = *(bf16x8*)(&hs[wid][l15][quad * 8]);
    bf16x8 a1 = *(bf16x8*)(&hs[wid][l15][32 + quad * 8]);
#pragma unroll
    for (int e = 0; e < 2; ++e) {
        float* dst = e ? e2 : e1;
#pragma unroll
        for (int nt = 0; nt < 2; ++nt) {
            f32x4 z = {0.f, 0.f, 0.f, 0.f};
            f32x4 ee = MFMA16(a0, wfr[e][nt][0], z, 0, 0, 0);
            ee = MFMA16(a1, wfr[e][nt][1], ee, 0, 0, 0);
#pragma unroll
            for (int r = 0; r < 4; ++r)
                dst[(row0 + quad * 4 + r) * 32 + 16 * nt + l15] = ee[r];
        }
    }
}

// ---------------- K3: a_mx 4x4/thread -> bf16, fused column sumsq ---------
__global__ __launch_bounds__(256) void amx_kernel(
    const float* __restrict__ e1, const float* __restrict__ e2,
    const float* __restrict__ b1p, const float* __restrict__ Vp,
    const float* __restrict__ bvp, unsigned short* __restrict__ amxb,
    float* __restrict__ nrmss)
{
    int bb = blockIdx.z;
    int i0 = blockIdx.y * 64, j0 = blockIdx.x * 64;
    __shared__ float e2s[64][33], e1s[64][33];
    __shared__ float Vs[32];
    __shared__ float red[16][68];
    int t = threadIdx.x;
    for (int u = t; u < 2048; u += 256) {
        int r = u >> 5, c = u & 31;
        e2s[r][c] = e2[(bb * 512 + i0 + r) * 32 + c];
        e1s[r][c] = e1[(bb * 512 + j0 + r) * 32 + c] + b1p[c];
    }
    if (t < 32) Vs[t] = Vp[t];
    __syncthreads();
    int ti = (t >> 4) * 4, tj = (t & 15) * 4;
    float acc[4][4] = {};
#define ELUF(v) ((v) > 0.f ? (v) : (__expf(v) - 1.f))
#pragma unroll
    for (int h = 0; h < 32; ++h) {
        float vv = Vs[h];
        float xi[4], yj[4];
#pragma unroll
        for (int p = 0; p < 4; ++p) xi[p] = e2s[ti + p][h];
#pragma unroll
        for (int q = 0; q < 4; ++q) yj[q] = e1s[tj + q][h];
#pragma unroll
        for (int p = 0; p < 4; ++p)
#pragma unroll
            for (int q = 0; q < 4; ++q)
                acc[p][q] += vv * ELUF(xi[p] + yj[q]);
    }
    float bv = bvp[0];
    float ss[4] = {0.f, 0.f, 0.f, 0.f};
#pragma unroll
    for (int p = 0; p < 4; ++p) {
        float v0 = acc[p][0] + bv, v1 = acc[p][1] + bv;
        float v2 = acc[p][2] + bv, v3 = acc[p][3] + bv;
        ushort4 o;
        o.x = f2bf(v0); o.y = f2bf(v1); o.z = f2bf(v2); o.w = f2bf(v3);
        *(ushort4*)(amxb + (bb * 512 + i0 + ti + p) * 512 + j0 + tj) = o;
        ss[0] += v0 * v0; ss[1] += v1 * v1; ss[2] += v2 * v2; ss[3] += v3 * v3;
    }
#pragma unroll
    for (int q = 0; q < 4; ++q) red[t >> 4][tj + q] = ss[q];
    __syncthreads();
    if (t < 64) {
        float s = 0.f;
#pragma unroll
        for (int g = 0; g < 16; ++g) s += red[g][t];
        atomicAdd(&nrmss[bb * 512 + j0 + t], s);
    }
}

// ---------------- K4: gemm_adjmix with inlined norm -----------------------
// C = (amx*rnrm_col) @ Wb ; c=sigmoid(C+wb) ; adjmix = adj*c + amx_s*(1-c)
__global__ __launch_bounds__(256) void gemm_adjmix(
    const unsigned short* __restrict__ amxb, const unsigned short* __restrict__ WbT,
    const float* __restrict__ wbp, const float* __restrict__ adj,
    const float* __restrict__ nrmss, unsigned short* __restrict__ adjmix)
{
    int bb = blockIdx.z;
    int i0 = blockIdx.y * 64, j0 = blockIdx.x * 64;
    __shared__ __align__(16) short As[64 * 72];
    __shared__ __align__(16) short Bs[64 * 72];
    __shared__ float rn[512];
    int t = threadIdx.x, w = t >> 6, lane = t & 63;
    int l15 = lane & 15, quad = lane >> 4;
    for (int u = t; u < 512; u += 256)
        rn[u] = 1.f / fmaxf(sqrtf(nrmss[bb * 512 + u]), 1e-12f);
    const unsigned short* Ag = amxb + bb * 262144;
    f32x4 acc[4] = {};
    for (int k0 = 0; k0 < 512; k0 += 64) {
        __syncthreads();
#pragma unroll
        for (int u0 = 0; u0 < 2; ++u0) {
            int u = t + u0 * 256;
            int i = u >> 3, o = u & 7;
            *(int4*)(Bs + i * 72 + o * 8) =
                *(const int4*)(WbT + (j0 + i) * 512 + k0 + o * 8);
            union { int4 v; unsigned short us[8]; } ur;
            ur.v = *(const int4*)(Ag + (i0 + i) * 512 + k0 + o * 8);
            union { int4 v; unsigned short us[8]; } ow;
#pragma unroll
            for (int c = 0; c < 8; ++c)
                ow.us[c] = f2bf(bf2f(ur.us[c]) * rn[k0 + o * 8 + c]);
            *(int4*)(As + i * 72 + o * 8) = ow.v;
        }
        __syncthreads();
        bf16x8 a0 = *(bf16x8*)(As + (16 * w + l15) * 72 + quad * 8);
        bf16x8 a1 = *(bf16x8*)(As + (16 * w + l15) * 72 + 32 + quad * 8);
#pragma unroll
        for (int nt = 0; nt < 4; ++nt) {
            bf16x8 b0 = *(bf16x8*)(Bs + (16 * nt + l15) * 72 + quad * 8);
            bf16x8 b1 = *(bf16x8*)(Bs + (16 * nt + l15) * 72 + 32 + quad * 8);
            acc[nt] = MFMA16(a0, b0, acc[nt], 0, 0, 0);
            acc[nt] = MFMA16(a1, b1, acc[nt], 0, 0, 0);
        }
    }
    float wb = wbp[0];
#pragma unroll
    for (int nt = 0; nt < 4; ++nt)
#pragma unroll
    for (int r = 0; r < 4; ++r) {
        int i = i0 + 16 * w + quad * 4 + r;
        int j = j0 + 16 * nt + l15;
        float s  = acc[nt][r] + wb;
        float cv = 1.f / (1.f + __expf(-s));
        float am = bf2f(Ag[i * 512 + j]) * rn[j];
        float ad = adj[i * 512 + j];
        adjmix[(bb * 512 + i) * 512 + j] = f2bf(ad * cv + am * (1.f - cv));
    }
}

// ---------------- K5: gemm_h1 + fused h1g = h1 @ gc2_w --------------------
__global__ __launch_bounds__(256) void gemm_h1(
    const unsigned short* __restrict__ adjmix, const unsigned short* __restrict__ rgT,
    const float* __restrict__ gc1_b, const float* __restrict__ gc2_w,
    float* __restrict__ h1g)
{
    int bb = blockIdx.y;
    int i0 = blockIdx.x * 32;
    __shared__ __align__(16) short As[32 * 72];
    __shared__ __align__(16) short Bs[64 * 72];
    __shared__ float h1s[32][72];
    int t = threadIdx.x, w = t >> 6, lane = t & 63;
    int l15 = lane & 15, quad = lane >> 4;
    int rt = w & 1, ntb = (w >> 1) * 2;
    const unsigned short* Ag = adjmix + bb * 262144;
    const unsigned short* Bg = rgT + bb * 32768;
    f32x4 acc[2] = {};
    for (int k0 = 0; k0 < 512; k0 += 64) {
        __syncthreads();
        {
            int i = t >> 3, o = t & 7;
            *(int4*)(As + i * 72 + o * 8) =
                *(const int4*)(Ag + (i0 + i) * 512 + k0 + o * 8);
        }
#pragma unroll
        for (int u0 = 0; u0 < 2; ++u0) {
            int u = t + u0 * 256;
            int i = u >> 3, o = u & 7;
            *(int4*)(Bs + i * 72 + o * 8) =
                *(const int4*)(Bg + i * 512 + k0 + o * 8);
        }
        __syncthreads();
        bf16x8 a0 = *(bf16x8*)(As + (16 * rt + l15) * 72 + quad * 8);
        bf16x8 a1 = *(bf16x8*)(As + (16 * rt + l15) * 72 + 32 + quad * 8);
#pragma unroll
        for (int q = 0; q < 2; ++q) {
            int nt = ntb + q;
            bf16x8 b0 = *(bf16x8*)(Bs + (16 * nt + l15) * 72 + quad * 8);
            bf16x8 b1 = *(bf16x8*)(Bs + (16 * nt + l15) * 72 + 32 + quad * 8);
            acc[q] = MFMA16(a0, b0, acc[q], 0, 0, 0);
            acc[q] = MFMA16(a1, b1, acc[q], 0, 0, 0);
        }
    }
#pragma unroll
    for (int q = 0; q < 2; ++q)
#pragma unroll
    for (int r = 0; r < 4; ++r) {
        int il = 16 * rt + quad * 4 + r;
        int j = 16 * (ntb + q) + l15;
        h1s[il][j] = fmaxf(acc[q][r] + gc1_b[j], 0.f);
    }
    __syncthreads();
    for (int u = t; u < 320; u += 256) {
        int row = u / 10, ns = u - row * 10;
        float a2 = 0.f;
#pragma unroll
        for (int j = 0; j < 64; ++j) a2 += h1s[row][j] * gc2_w[j * 10 + ns];
        h1g[(bb * 512 + i0 + row) * 10 + ns] = a2;
    }
}

// ---------------- K6: ospout = relu(adjmix@h1g+b) -> final projection -----
__global__ __launch_bounds__(256) void ospout_kernel(
    const unsigned short* __restrict__ adjmix, const float* __restrict__ h1g,
    const float* __restrict__ gc2_b, const float* __restrict__ lh,
    const float* __restrict__ out_w, const float* __restrict__ out_b,
    float* __restrict__ out)
{
    int r0 = blockIdx.x * 4;
    int bb = r0 >> 9;
    int wid = threadIdx.x >> 6, lane = threadIdx.x & 63;
    __shared__ float Bsm[10][512];
    __shared__ float ow[8][80];
    __shared__ float ob[8], g2b[10];
    for (int u = threadIdx.x; u < 5120; u += 256) {
        int k = u / 10, ns = u - k * 10;
        Bsm[ns][k] = h1g[bb * 5120 + u];
    }
    if (threadIdx.x < 8)  ob[threadIdx.x]  = out_b[threadIdx.x];
    if (threadIdx.x < 10) g2b[threadIdx.x] = gc2_b[threadIdx.x];
    for (int u = threadIdx.x; u < 592; u += 256) {
        int hh = u / 74, c = u - hh * 74;
        ow[hh][c] = out_w[u];
    }
    __syncthreads();
    int row = r0 + wid, m = row & 511;
    const unsigned short* Ar = adjmix + row * 512;
    float a[8];
#pragma unroll
    for (int q = 0; q < 8; ++q) a[q] = bf2f(Ar[lane + 64 * q]);
    float os[10];
#pragma unroll
    for (int ns = 0; ns < 10; ++ns) {
        float s = 0.f;
#pragma unroll
        for (int q = 0; q < 8; ++q) s += a[q] * Bsm[ns][lane + 64 * q];
#pragma unroll
        for (int off = 32; off; off >>= 1) s += __shfl_xor(s, off);
        os[ns] = fmaxf(s + g2b[ns], 0.f);
    }
    float lv = lh[row * 64 + lane];
#pragma unroll
    for (int hh = 0; hh < 8; ++hh) {
        float t1 = lv * ow[hh][10 + lane];
#pragma unroll
        for (int off = 32; off; off >>= 1) t1 += __shfl_xor(t1, off);
        if (lane == hh) {
            float acc = ob[hh] + t1;
#pragma unroll
            for (int ns = 0; ns < 10; ++ns) acc += os[ns] * ow[hh][ns];
            out[bb * 4096 + hh * 512 + m] = acc;
        }
    }
}

// ---------------- launch ---------------------------------------------------
extern "C" void kernel_launch(void* const* d_in, const int* in_sizes, int n_in,
                              void* d_out, int out_size, void* d_ws, size_t ws_size,
                              hipStream_t stream)
{
    const float* x       = (const float*)d_in[0];
    const float* adj     = (const float*)d_in[1];
    const float* Wih     = (const float*)d_in[2];
    const float* Whh     = (const float*)d_in[3];
    const float* bih     = (const float*)d_in[4];
    const float* bhh     = (const float*)d_in[5];
    const float* W1      = (const float*)d_in[6];
    const float* W2      = (const float*)d_in[7];
    const float* b1      = (const float*)d_in[8];
    const float* V       = (const float*)d_in[9];
    const float* bv      = (const float*)d_in[10];
    const float* Wb      = (const float*)d_in[11];
    const float* wb      = (const float*)d_in[12];
    const float* conv_w  = (const float*)d_in[13];
    const float* conv_b  = (const float*)d_in[14];
    const float* convl_w = (const float*)d_in[15];
    const float* convl_b = (const float*)d_in[16];
    const float* gc1_w   = (const float*)d_in[17];
    const float* gc1_b   = (const float*)d_in[18];
    const float* gc2_w   = (const float*)d_in[19];
    const float* gc2_b   = (const float*)d_in[20];
    const float* out_w   = (const float*)d_in[21];
    const float* out_b   = (const float*)d_in[22];

    float* ws    = (float*)d_ws;
    float* lh    = ws;                  // 524288
    float* e1    = lh + 524288;         // 262144
    float* e2    = e1 + 262144;         // 262144
    float* nrmss = e2 + 262144;         // 8192
    float* h1g   = nrmss + 8192;        // 81920
    unsigned short* amxb    = (unsigned short*)(h1g + 81920);  // 4194304
    unsigned short* adjmixb = amxb + 4194304;                  // 4194304
    unsigned short* WbT     = adjmixb + 4194304;               // 262144
    unsigned short* rgT     = WbT + 262144;                    // 524288

    prep_kernel<<<544, 256, 0, stream>>>(x, conv_w, conv_b, convl_w, convl_b,
                                         gc1_w, rgT, Wb, WbT, nrmss);
    rnn_kernel<<<128, 256, 0, stream>>>(x, Wih, Whh, bih, bhh, W1, W2,
                                        lh, e1, e2);
    amx_kernel<<<dim3(8, 8, 16), 256, 0, stream>>>(e1, e2, b1, V, bv,
                                                   amxb, nrmss);
    gemm_adjmix<<<dim3(8, 8, 16), 256, 0, stream>>>(amxb, WbT, wb, adj,
                                                    nrmss, adjmixb);
    gemm_h1<<<dim3(16, 16), 256, 0, stream>>>(adjmixb, rgT, gc1_b, gc2_w, h1g);
    ospout_kernel<<<2048, 256, 0, stream>>>(adjmixb, h1g, gc2_b, lh,
                                            out_w, out_b, (float*)d_out);
}

// Round 6
// 206.424 us; speedup vs baseline: 2.0971x; 1.0674x over previous
//
#include <hip/hip_runtime.h>

// dims: B=16 W=32 M=512 NH=64 HALF=32 K=8 H=8 LK=16 LOUT=2 NSP=10 GCIN=24
// rows = B*M = 8192. Reference dtypes fp32; bf16 internally for MFMA.
// 5 dispatches: fused1(rnn+e | conv+rg | wbt | zero), amx, gemm_adjmix,
// gemm_h1(+h1g), ospout(+final proj).

typedef __attribute__((ext_vector_type(8))) short bf16x8;
typedef __attribute__((ext_vector_type(4))) float f32x4;
#define MFMA16 __builtin_amdgcn_mfma_f32_16x16x32_bf16

__device__ __forceinline__ unsigned short f2bf(float f) {
    unsigned u = __float_as_uint(f);
    u += 0x7fff + ((u >> 16) & 1);          // RNE
    return (unsigned short)(u >> 16);
}
__device__ __forceinline__ float bf2f(unsigned short h) {
    return __uint_as_float(((unsigned)h) << 16);
}
__device__ __forceinline__ float fast_tanh(float x) {
    float e = __expf(2.f * x);
    return 1.f - 2.f / (e + 1.f);
}

// ---------------- K1: fused1 ----------------------------------------------
// blocks [0,128): RNN via MFMA + e1/e2 epilogue (64 series/block)
// blocks [128,384): conv features + rg projection (32 rows/block)
// blocks [384,640): Wb transpose->bf16
// blocks [640,672): zero nrmss
__global__ __launch_bounds__(256) void fused1_kernel(
    const float* __restrict__ x, const float* __restrict__ Wih,
    const float* __restrict__ Whh, const float* __restrict__ bih,
    const float* __restrict__ bhh, const float* __restrict__ W1,
    const float* __restrict__ W2, float* __restrict__ lh,
    float* __restrict__ e1, float* __restrict__ e2,
    const float* __restrict__ conv_w, const float* __restrict__ conv_b,
    const float* __restrict__ convl_w, const float* __restrict__ convl_b,
    const float* __restrict__ gc1_w, unsigned short* __restrict__ rgT,
    const float* __restrict__ Wb, unsigned short* __restrict__ WbT,
    float* __restrict__ nrmss)
{
    __shared__ __align__(16) char smem[17408];
    int blk = blockIdx.x, t = threadIdx.x;

    if (blk < 128) {
        // ---------------- RNN ----------------
        int wid = t >> 6, lane = t & 63;
        int l15 = lane & 15, quad = lane >> 4;
        int rowblk = blk * 64;
        int row0 = rowblk + wid * 16;
        int b = rowblk >> 9, mb = rowblk & 511;
        float* xs = (float*)smem;                              // [32][64]
        unsigned short* hs = (unsigned short*)(smem + 8192);   // [4][16][72]

        bf16x8 afr[4][2];
#pragma unroll
        for (int mt = 0; mt < 4; ++mt)
#pragma unroll
            for (int hf = 0; hf < 2; ++hf) {
                const float* src = Whh + (16 * mt + l15) * 64 + 32 * hf + quad * 8;
                union { bf16x8 v; unsigned short u[8]; } tmp;
#pragma unroll
                for (int j = 0; j < 8; ++j) tmp.u[j] = f2bf(src[j]);
                afr[mt][hf] = tmp.v;
            }
        bf16x8 wfr[2][2][2];
#pragma unroll
        for (int e = 0; e < 2; ++e)
#pragma unroll
            for (int nt = 0; nt < 2; ++nt)
#pragma unroll
                for (int kf = 0; kf < 2; ++kf) {
                    const float* Wsrc = (e ? W2 : W1);
                    const float* src = Wsrc + (16 * nt + l15) * 64 + 32 * kf + quad * 8;
                    union { bf16x8 v; unsigned short u[8]; } tmp;
#pragma unroll
                    for (int j = 0; j < 8; ++j) tmp.u[j] = f2bf(src[j]);
                    wfr[e][nt][kf] = tmp.v;
                }
        float wihv[4][4], bsv[4][4];
#pragma unroll
        for (int mt = 0; mt < 4; ++mt)
#pragma unroll
            for (int r = 0; r < 4; ++r) {
                int n = 16 * mt + quad * 4 + r;
                wihv[mt][r] = Wih[n];
                bsv[mt][r]  = bih[n] + bhh[n];
            }

        for (int u = t; u < 2048; u += 256) {
            int tt = u >> 6, c = u & 63;
            xs[tt * 64 + c] = x[(b * 32 + tt) * 512 + mb + c];
        }
        for (int u = lane; u < 1152; u += 64) hs[wid * 1152 + u] = 0;
        __syncthreads();

        int mloc = wid * 16;
        unsigned short* hw0 = hs + wid * 1152;
        float th[4][4];
        for (int tstep = 0; tstep < 32; ++tstep) {
            bf16x8 b0 = *(bf16x8*)(hw0 + l15 * 72 + quad * 8);
            bf16x8 b1 = *(bf16x8*)(hw0 + l15 * 72 + 32 + quad * 8);
            float xt = xs[tstep * 64 + mloc + l15];
            f32x4 acc[4];
#pragma unroll
            for (int mt = 0; mt < 4; ++mt) {
                f32x4 z = {0.f, 0.f, 0.f, 0.f};
                acc[mt] = MFMA16(afr[mt][0], b0, z, 0, 0, 0);
                acc[mt] = MFMA16(afr[mt][1], b1, acc[mt], 0, 0, 0);
            }
#pragma unroll
            for (int mt = 0; mt < 4; ++mt) {
                ushort4 hwv;
#pragma unroll
                for (int r = 0; r < 4; ++r)
                    th[mt][r] = fast_tanh(acc[mt][r] + xt * wihv[mt][r] + bsv[mt][r]);
                hwv.x = f2bf(th[mt][0]); hwv.y = f2bf(th[mt][1]);
                hwv.z = f2bf(th[mt][2]); hwv.w = f2bf(th[mt][3]);
                *(ushort4*)(hw0 + l15 * 72 + 16 * mt + quad * 4) = hwv;
            }
        }
#pragma unroll
        for (int mt = 0; mt < 4; ++mt)
            *(float4*)(lh + (row0 + l15) * 64 + 16 * mt + quad * 4) =
                make_float4(th[mt][0], th[mt][1], th[mt][2], th[mt][3]);

        bf16x8 a0 = *(bf16x8*)(hw0 + l15 * 72 + quad * 8);
        bf16x8 a1 = *(bf16x8*)(hw0 + l15 * 72 + 32 + quad * 8);
#pragma unroll
        for (int e = 0; e < 2; ++e) {
            float* dst = e ? e2 : e1;
#pragma unroll
            for (int nt = 0; nt < 2; ++nt) {
                f32x4 z = {0.f, 0.f, 0.f, 0.f};
                f32x4 ee = MFMA16(a0, wfr[e][nt][0], z, 0, 0, 0);
                ee = MFMA16(a1, wfr[e][nt][1], ee, 0, 0, 0);
#pragma unroll
                for (int r = 0; r < 4; ++r)
                    dst[(row0 + quad * 4 + r) * 32 + 16 * nt + l15] = ee[r];
            }
        }
    } else if (blk < 384) {
        // ---------------- conv + rg ----------------
        int blk2 = blk - 128;
        int r0 = blk2 * 32;
        int bb = r0 >> 9, m0 = r0 & 511;
        float* xs  = (float*)smem;              // [32][32]
        float* rrs = (float*)(smem + 4096);     // [32][25]
        for (int u = t; u < 1024; u += 256) {
            int w = u >> 5, mm = u & 31;
            xs[u] = x[(bb * 32 + w) * 512 + m0 + mm];
        }
        __syncthreads();
        {
            int k = t & 7, rl = t >> 3;
            float s = conv_b[k];
            for (int w = 0; w < 32; ++w) s += xs[w * 32 + rl] * conv_w[k * 32 + w];
            float l0 = convl_b[k], l1 = l0;
            for (int tt = 0; tt < 16; ++tt) {
                float wv = convl_w[k * 16 + tt];
                l0 += xs[(2 * tt) * 32 + rl] * wv;
                l1 += xs[(2 * tt + 1) * 32 + rl] * wv;
            }
            rrs[rl * 25 + k * 3 + 0] = fmaxf(s, 0.f);
            rrs[rl * 25 + k * 3 + 1] = fmaxf(l0, 0.f);
            rrs[rl * 25 + k * 3 + 2] = fmaxf(l1, 0.f);
        }
        __syncthreads();
        int rl = t & 31, nb = t >> 5;
#pragma unroll
        for (int q = 0; q < 8; ++q) {
            int n = nb * 8 + q;
            float acc = 0.f;
#pragma unroll
            for (int c = 0; c < 24; ++c) acc += rrs[rl * 25 + c] * gc1_w[c * 64 + n];
            rgT[bb * 32768 + n * 512 + m0 + rl] = f2bf(acc);
        }
    } else if (blk < 640) {
        // ---------------- Wb transpose ----------------
        int bid = blk - 384;
        int nb = (bid & 15) * 32, kb = (bid >> 4) * 32;
        float* tile = (float*)smem;             // [32][33]
        for (int u = t; u < 1024; u += 256) {
            int r = u >> 5, c = u & 31;
            tile[r * 33 + c] = Wb[(kb + r) * 512 + nb + c];
        }
        __syncthreads();
        for (int u = t; u < 1024; u += 256) {
            int r = u >> 5, c = u & 31;
            WbT[(nb + r) * 512 + kb + c] = f2bf(tile[c * 33 + r]);
        }
    } else {
        nrmss[(blk - 640) * 256 + t] = 0.f;
    }
}

// ---------------- K2: a_mx 4x4/thread, factorized exp, fused sumsq --------
__global__ __launch_bounds__(256) void amx_kernel(
    const float* __restrict__ e1, const float* __restrict__ e2,
    const float* __restrict__ b1p, const float* __restrict__ Vp,
    const float* __restrict__ bvp, unsigned short* __restrict__ amxb,
    float* __restrict__ nrmss)
{
    int bb = blockIdx.z;
    int i0 = blockIdx.y * 64, j0 = blockIdx.x * 64;
    __shared__ float e2s[64][33], e1s[64][33];
    __shared__ float Vs[32];
    __shared__ float red[16][68];
    int t = threadIdx.x;
    for (int u = t; u < 2048; u += 256) {
        int r = u >> 5, c = u & 31;
        e2s[r][c] = e2[(bb * 512 + i0 + r) * 32 + c];
        e1s[r][c] = e1[(bb * 512 + j0 + r) * 32 + c] + b1p[c];
    }
    if (t < 32) Vs[t] = Vp[t];
    __syncthreads();
    int ti = (t >> 4) * 4, tj = (t & 15) * 4;
    float acc[4][4] = {};
#pragma unroll
    for (int h = 0; h < 32; ++h) {
        float vv = Vs[h];
        float xi[4], yj[4], Exi[4], Eyj[4];
#pragma unroll
        for (int p = 0; p < 4; ++p) { xi[p] = e2s[ti + p][h]; Exi[p] = __expf(xi[p]); }
#pragma unroll
        for (int q = 0; q < 4; ++q) { yj[q] = e1s[tj + q][h]; Eyj[q] = __expf(yj[q]); }
#pragma unroll
        for (int p = 0; p < 4; ++p)
#pragma unroll
            for (int q = 0; q < 4; ++q) {
                float v = xi[p] + yj[q];
                float prod = Exi[p] * Eyj[q];
                float el = v > 0.f ? v : prod - 1.f;  // exp(xi+yj)=Exi*Eyj
                acc[p][q] += vv * el;
            }
    }
    float bv = bvp[0];
    float ss[4] = {0.f, 0.f, 0.f, 0.f};
#pragma unroll
    for (int p = 0; p < 4; ++p) {
        float v0 = acc[p][0] + bv, v1 = acc[p][1] + bv;
        float v2 = acc[p][2] + bv, v3 = acc[p][3] + bv;
        ushort4 o;
        o.x = f2bf(v0); o.y = f2bf(v1); o.z = f2bf(v2); o.w = f2bf(v3);
        *(ushort4*)(amxb + (bb * 512 + i0 + ti + p) * 512 + j0 + tj) = o;
        ss[0] += v0 * v0; ss[1] += v1 * v1; ss[2] += v2 * v2; ss[3] += v3 * v3;
    }
#pragma unroll
    for (int q = 0; q < 4; ++q) red[t >> 4][tj + q] = ss[q];
    __syncthreads();
    if (t < 64) {
        float s = 0.f;
#pragma unroll
        for (int g = 0; g < 16; ++g) s += red[g][t];
        atomicAdd(&nrmss[bb * 512 + j0 + t], s);
    }
}

// ---------------- K3: gemm_adjmix, wrap-ordered K so last A-tile == j0 ----
__global__ __launch_bounds__(256) void gemm_adjmix(
    const unsigned short* __restrict__ amxb, const unsigned short* __restrict__ WbT,
    const float* __restrict__ wbp, const float* __restrict__ adj,
    const float* __restrict__ nrmss, unsigned short* __restrict__ adjmix)
{
    int bb = blockIdx.z;
    int i0 = blockIdx.y * 64, j0 = blockIdx.x * 64;
    __shared__ __align__(16) short As[64 * 72];
    __shared__ __align__(16) short Bs[64 * 72];
    __shared__ float rn[512];
    int t = threadIdx.x, w = t >> 6, lane = t & 63;
    int l15 = lane & 15, quad = lane >> 4;
    for (int u = t; u < 512; u += 256)
        rn[u] = 1.f / fmaxf(sqrtf(nrmss[bb * 512 + u]), 1e-12f);
    const unsigned short* Ag = amxb + bb * 262144;
    f32x4 acc[4] = {};
    for (int kk = 1; kk <= 8; ++kk) {
        int k0 = (j0 + 64 * kk) & 511;      // last iter: k0 == j0
        __syncthreads();
#pragma unroll
        for (int u0 = 0; u0 < 2; ++u0) {
            int u = t + u0 * 256;
            int i = u >> 3, o = u & 7;
            *(int4*)(Bs + i * 72 + o * 8) =
                *(const int4*)(WbT + (j0 + i) * 512 + k0 + o * 8);
            union { int4 v; unsigned short us[8]; } ur;
            ur.v = *(const int4*)(Ag + (i0 + i) * 512 + k0 + o * 8);
            union { int4 v; unsigned short us[8]; } ow;
#pragma unroll
            for (int c = 0; c < 8; ++c)
                ow.us[c] = f2bf(bf2f(ur.us[c]) * rn[k0 + o * 8 + c]);
            *(int4*)(As + i * 72 + o * 8) = ow.v;
        }
        __syncthreads();
        bf16x8 a0 = *(bf16x8*)(As + (16 * w + l15) * 72 + quad * 8);
        bf16x8 a1 = *(bf16x8*)(As + (16 * w + l15) * 72 + 32 + quad * 8);
#pragma unroll
        for (int nt = 0; nt < 4; ++nt) {
            bf16x8 b0 = *(bf16x8*)(Bs + (16 * nt + l15) * 72 + quad * 8);
            bf16x8 b1 = *(bf16x8*)(Bs + (16 * nt + l15) * 72 + 32 + quad * 8);
            acc[nt] = MFMA16(a0, b0, acc[nt], 0, 0, 0);
            acc[nt] = MFMA16(a1, b1, acc[nt], 0, 0, 0);
        }
    }
    // As now holds scaled amx(i0:64, j0:64) in LDS
    float wb = wbp[0];
#pragma unroll
    for (int nt = 0; nt < 4; ++nt)
#pragma unroll
    for (int r = 0; r < 4; ++r) {
        int il = 16 * w + quad * 4 + r;
        int jl = 16 * nt + l15;
        int i = i0 + il, j = j0 + jl;
        float s  = acc[nt][r] + wb;
        float cv = 1.f / (1.f + __expf(-s));
        float am = bf2f((unsigned short)As[il * 72 + jl]);
        float ad = adj[i * 512 + j];
        adjmix[(bb * 512 + i) * 512 + j] = f2bf(ad * cv + am * (1.f - cv));
    }
}

// ---------------- K4: gemm_h1 + fused h1g = h1 @ gc2_w --------------------
__global__ __launch_bounds__(256) void gemm_h1(
    const unsigned short* __restrict__ adjmix, const unsigned short* __restrict__ rgT,
    const float* __restrict__ gc1_b, const float* __restrict__ gc2_w,
    float* __restrict__ h1g)
{
    int bb = blockIdx.y;
    int i0 = blockIdx.x * 32;
    __shared__ __align__(16) short As[32 * 72];
    __shared__ __align__(16) short Bs[64 * 72];
    __shared__ float h1s[32][72];
    int t = threadIdx.x, w = t >> 6, lane = t & 63;
    int l15 = lane & 15, quad = lane >> 4;
    int rt = w & 1, ntb = (w >> 1) * 2;
    const unsigned short* Ag = adjmix + bb * 262144;
    const unsigned short* Bg = rgT + bb * 32768;
    f32x4 acc[2] = {};
    for (int k0 = 0; k0 < 512; k0 += 64) {
        __syncthreads();
        {
            int i = t >> 3, o = t & 7;
            *(int4*)(As + i * 72 + o * 8) =
                *(const int4*)(Ag + (i0 + i) * 512 + k0 + o * 8);
        }
#pragma unroll
        for (int u0 = 0; u0 < 2; ++u0) {
            int u = t + u0 * 256;
            int i = u >> 3, o = u & 7;
            *(int4*)(Bs + i * 72 + o * 8) =
                *(const int4*)(Bg + i * 512 + k0 + o * 8);
        }
        __syncthreads();
        bf16x8 a0 = *(bf16x8*)(As + (16 * rt + l15) * 72 + quad * 8);
        bf16x8 a1 = *(bf16x8*)(As + (16 * rt + l15) * 72 + 32 + quad * 8);
#pragma unroll
        for (int q = 0; q < 2; ++q) {
            int nt = ntb + q;
            bf16x8 b0 = *(bf16x8*)(Bs + (16 * nt + l15) * 72 + quad * 8);
            bf16x8 b1 = *(bf16x8*)(Bs + (16 * nt + l15) * 72 + 32 + quad * 8);
            acc[q] = MFMA16(a0, b0, acc[q], 0, 0, 0);
            acc[q] = MFMA16(a1, b1, acc[q], 0, 0, 0);
        }
    }
#pragma unroll
    for (int q = 0; q < 2; ++q)
#pragma unroll
    for (int r = 0; r < 4; ++r) {
        int il = 16 * rt + quad * 4 + r;
        int j = 16 * (ntb + q) + l15;
        h1s[il][j] = fmaxf(acc[q][r] + gc1_b[j], 0.f);
    }
    __syncthreads();
    for (int u = t; u < 320; u += 256) {
        int row = u / 10, ns = u - row * 10;
        float a2 = 0.f;
#pragma unroll
        for (int j = 0; j < 64; ++j) a2 += h1s[row][j] * gc2_w[j * 10 + ns];
        h1g[(bb * 512 + i0 + row) * 10 + ns] = a2;
    }
}

// ---------------- K5: ospout, 8 rows/block --------------------------------
__global__ __launch_bounds__(256) void ospout_kernel(
    const unsigned short* __restrict__ adjmix, const float* __restrict__ h1g,
    const float* __restrict__ gc2_b, const float* __restrict__ lh,
    const float* __restrict__ out_w, const float* __restrict__ out_b,
    float* __restrict__ out)
{
    int r0 = blockIdx.x * 8;
    int bb = r0 >> 9;
    int wid = threadIdx.x >> 6, lane = threadIdx.x & 63;
    __shared__ float Bsm[10][512];
    __shared__ float ow[8][80];
    __shared__ float ob[8], g2b[10];
    for (int u = threadIdx.x; u < 5120; u += 256) {
        int k = u / 10, ns = u - k * 10;
        Bsm[ns][k] = h1g[bb * 5120 + u];
    }
    if (threadIdx.x < 8)  ob[threadIdx.x]  = out_b[threadIdx.x];
    if (threadIdx.x < 10) g2b[threadIdx.x] = gc2_b[threadIdx.x];
    for (int u = threadIdx.x; u < 592; u += 256) {
        int hh = u / 74, c = u - hh * 74;
        ow[hh][c] = out_w[u];
    }
    __syncthreads();
#pragma unroll
    for (int half = 0; half < 2; ++half) {
        int row = r0 + half * 4 + wid, m = row & 511;
        const unsigned short* Ar = adjmix + row * 512;
        float a[8];
#pragma unroll
        for (int q = 0; q < 8; ++q) a[q] = bf2f(Ar[lane + 64 * q]);
        float os[10];
#pragma unroll
        for (int ns = 0; ns < 10; ++ns) {
            float s = 0.f;
#pragma unroll
            for (int q = 0; q < 8; ++q) s += a[q] * Bsm[ns][lane + 64 * q];
#pragma unroll
            for (int off = 32; off; off >>= 1) s += __shfl_xor(s, off);
            os[ns] = fmaxf(s + g2b[ns], 0.f);
        }
        float lv = lh[row * 64 + lane];
#pragma unroll
        for (int hh = 0; hh < 8; ++hh) {
            float t1 = lv * ow[hh][10 + lane];
#pragma unroll
            for (int off = 32; off; off >>= 1) t1 += __shfl_xor(t1, off);
            if (lane == hh) {
                float acc = ob[hh] + t1;
#pragma unroll
                for (int ns = 0; ns < 10; ++ns) acc += os[ns] * ow[hh][ns];
                out[bb * 4096 + hh * 512 + m] = acc;
            }
        }
    }
}

// ---------------- launch ---------------------------------------------------
extern "C" void kernel_launch(void* const* d_in, const int* in_sizes, int n_in,
                              void* d_out, int out_size, void* d_ws, size_t ws_size,
                              hipStream_t stream)
{
    const float* x       = (const float*)d_in[0];
    const float* adj     = (const float*)d_in[1];
    const float* Wih     = (const float*)d_in[2];
    const float* Whh     = (const float*)d_in[3];
    const float* bih     = (const float*)d_in[4];
    const float* bhh     = (const float*)d_in[5];
    const float* W1      = (const float*)d_in[6];
    const float* W2      = (const float*)d_in[7];
    const float* b1      = (const float*)d_in[8];
    const float* V       = (const float*)d_in[9];
    const float* bv      = (const float*)d_in[10];
    const float* Wb      = (const float*)d_in[11];
    const float* wb      = (const float*)d_in[12];
    const float* conv_w  = (const float*)d_in[13];
    const float* conv_b  = (const float*)d_in[14];
    const float* convl_w = (const float*)d_in[15];
    const float* convl_b = (const float*)d_in[16];
    const float* gc1_w   = (const float*)d_in[17];
    const float* gc1_b   = (const float*)d_in[18];
    const float* gc2_w   = (const float*)d_in[19];
    const float* gc2_b   = (const float*)d_in[20];
    const float* out_w   = (const float*)d_in[21];
    const float* out_b   = (const float*)d_in[22];

    float* ws    = (float*)d_ws;
    float* lh    = ws;                  // 524288
    float* e1    = lh + 524288;         // 262144
    float* e2    = e1 + 262144;         // 262144
    float* nrmss = e2 + 262144;         // 8192
    float* h1g   = nrmss + 8192;        // 81920
    unsigned short* amxb    = (unsigned short*)(h1g + 81920);  // 4194304
    unsigned short* adjmixb = amxb + 4194304;                  // 4194304
    unsigned short* WbT     = adjmixb + 4194304;               // 262144
    unsigned short* rgT     = WbT + 262144;                    // 524288

    fused1_kernel<<<672, 256, 0, stream>>>(
        x, Wih, Whh, bih, bhh, W1, W2, lh, e1, e2,
        conv_w, conv_b, convl_w, convl_b, gc1_w, rgT, Wb, WbT, nrmss);
    amx_kernel<<<dim3(8, 8, 16), 256, 0, stream>>>(e1, e2, b1, V, bv,
                                                   amxb, nrmss);
    gemm_adjmix<<<dim3(8, 8, 16), 256, 0, stream>>>(amxb, WbT, wb, adj,
                                                    nrmss, adjmixb);
    gemm_h1<<<dim3(16, 16), 256, 0, stream>>>(adjmixb, rgT, gc1_b, gc2_w, h1g);
    ospout_kernel<<<1024, 256, 0, stream>>>(adjmixb, h1g, gc2_b, lh,
                                            out_w, out_b, (float*)d_out);
}

// Round 7
// 206.285 us; speedup vs baseline: 2.0985x; 1.0007x over previous
//
#include <hip/hip_runtime.h>

// dims: B=16 W=32 M=512 NH=64 HALF=32 K=8 H=8 LK=16 LOUT=2 NSP=10 GCIN=24
// rows = B*M = 8192. Reference dtypes fp32; bf16 internally for MFMA.
// 5 dispatches: fused1(rnn+e+conv+rg | wbt | zero), amx, gemm_adjmix,
// gemm_h1(+h1g), ospout(+final proj).

typedef __attribute__((ext_vector_type(8))) short bf16x8;
typedef __attribute__((ext_vector_type(4))) float f32x4;
#define MFMA16 __builtin_amdgcn_mfma_f32_16x16x32_bf16

__device__ __forceinline__ unsigned short f2bf(float f) {
    unsigned u = __float_as_uint(f);
    u += 0x7fff + ((u >> 16) & 1);          // RNE
    return (unsigned short)(u >> 16);
}
__device__ __forceinline__ float bf2f(unsigned short h) {
    return __uint_as_float(((unsigned)h) << 16);
}
__device__ __forceinline__ float fast_tanh(float x) {
    float e = __expf(2.f * x);
    return 1.f - 2.f / (e + 1.f);
}

// ---------------- K1: fused1 ----------------------------------------------
// blocks [0,256): 32 series each. Waves 0-1: RNN via MFMA + e1/e2 epilogue
//                 (16 series/wave). Waves 2-3: conv+rg for the same 32 rows
//                 (intra-wave producer/consumer; hides under serial RNN).
// blocks [256,512): Wb transpose->bf16
// blocks [512,544): zero nrmss
__global__ __launch_bounds__(256) void fused1_kernel(
    const float* __restrict__ x, const float* __restrict__ Wih,
    const float* __restrict__ Whh, const float* __restrict__ bih,
    const float* __restrict__ bhh, const float* __restrict__ W1,
    const float* __restrict__ W2, float* __restrict__ lh,
    float* __restrict__ e1, float* __restrict__ e2,
    const float* __restrict__ conv_w, const float* __restrict__ conv_b,
    const float* __restrict__ convl_w, const float* __restrict__ convl_b,
    const float* __restrict__ gc1_w, unsigned short* __restrict__ rgT,
    const float* __restrict__ Wb, unsigned short* __restrict__ WbT,
    float* __restrict__ nrmss)
{
    __shared__ __align__(16) char smem[12160];
    int blk = blockIdx.x, t = threadIdx.x;

    if (blk < 256) {
        int wid = t >> 6, lane = t & 63;
        int rowblk = blk * 32;
        int b = rowblk >> 9, mb = rowblk & 511;
        float* xs = (float*)smem;                               // [32][32]
        unsigned short* hs = (unsigned short*)(smem + 4096);    // [2][16][72]
        float* rrs = (float*)(smem + 8704);                     // [32][25] (conv feats)

        // cooperative x stage (all 4 waves)
        for (int u = t; u < 1024; u += 256) {
            int tt = u >> 5, c = u & 31;
            xs[tt * 32 + c] = x[(b * 32 + tt) * 512 + mb + c];
        }
        for (int u = t; u < 2304; u += 256) hs[u] = 0;
        __syncthreads();

        if (wid < 2) {
            // ---------------- RNN (waves 0,1; 16 series each) ----------
            int l15 = lane & 15, quad = lane >> 4;
            int row0 = rowblk + wid * 16;
            unsigned short* hw0 = hs + wid * 1152;

            bf16x8 afr[4][2];
#pragma unroll
            for (int mt = 0; mt < 4; ++mt)
#pragma unroll
                for (int hf = 0; hf < 2; ++hf) {
                    const float* src = Whh + (16 * mt + l15) * 64 + 32 * hf + quad * 8;
                    union { bf16x8 v; unsigned short u[8]; } tmp;
#pragma unroll
                    for (int j = 0; j < 8; ++j) tmp.u[j] = f2bf(src[j]);
                    afr[mt][hf] = tmp.v;
                }
            bf16x8 wfr[2][2][2];
#pragma unroll
            for (int e = 0; e < 2; ++e)
#pragma unroll
                for (int nt = 0; nt < 2; ++nt)
#pragma unroll
                    for (int kf = 0; kf < 2; ++kf) {
                        const float* Wsrc = (e ? W2 : W1);
                        const float* src = Wsrc + (16 * nt + l15) * 64 + 32 * kf + quad * 8;
                        union { bf16x8 v; unsigned short u[8]; } tmp;
#pragma unroll
                        for (int j = 0; j < 8; ++j) tmp.u[j] = f2bf(src[j]);
                        wfr[e][nt][kf] = tmp.v;
                    }
            float wihv[4][4], bsv[4][4];
#pragma unroll
            for (int mt = 0; mt < 4; ++mt)
#pragma unroll
                for (int r = 0; r < 4; ++r) {
                    int n = 16 * mt + quad * 4 + r;
                    wihv[mt][r] = Wih[n];
                    bsv[mt][r]  = bih[n] + bhh[n];
                }

            float th[4][4];
            for (int tstep = 0; tstep < 32; ++tstep) {
                bf16x8 b0 = *(bf16x8*)(hw0 + l15 * 72 + quad * 8);
                bf16x8 b1 = *(bf16x8*)(hw0 + l15 * 72 + 32 + quad * 8);
                float xt = xs[tstep * 32 + wid * 16 + l15];
                f32x4 acc[4];
#pragma unroll
                for (int mt = 0; mt < 4; ++mt) {
                    f32x4 z = {0.f, 0.f, 0.f, 0.f};
                    acc[mt] = MFMA16(afr[mt][0], b0, z, 0, 0, 0);
                    acc[mt] = MFMA16(afr[mt][1], b1, acc[mt], 0, 0, 0);
                }
#pragma unroll
                for (int mt = 0; mt < 4; ++mt) {
                    ushort4 hwv;
#pragma unroll
                    for (int r = 0; r < 4; ++r)
                        th[mt][r] = fast_tanh(acc[mt][r] + xt * wihv[mt][r] + bsv[mt][r]);
                    hwv.x = f2bf(th[mt][0]); hwv.y = f2bf(th[mt][1]);
                    hwv.z = f2bf(th[mt][2]); hwv.w = f2bf(th[mt][3]);
                    *(ushort4*)(hw0 + l15 * 72 + 16 * mt + quad * 4) = hwv;
                }
            }
#pragma unroll
            for (int mt = 0; mt < 4; ++mt)
                *(float4*)(lh + (row0 + l15) * 64 + 16 * mt + quad * 4) =
                    make_float4(th[mt][0], th[mt][1], th[mt][2], th[mt][3]);

            bf16x8 a0 = *(bf16x8*)(hw0 + l15 * 72 + quad * 8);
            bf16x8 a1 = *(bf16x8*)(hw0 + l15 * 72 + 32 + quad * 8);
#pragma unroll
            for (int e = 0; e < 2; ++e) {
                float* dst = e ? e2 : e1;
#pragma unroll
                for (int nt = 0; nt < 2; ++nt) {
                    f32x4 z = {0.f, 0.f, 0.f, 0.f};
                    f32x4 ee = MFMA16(a0, wfr[e][nt][0], z, 0, 0, 0);
                    ee = MFMA16(a1, wfr[e][nt][1], ee, 0, 0, 0);
#pragma unroll
                    for (int r = 0; r < 4; ++r)
                        dst[(row0 + quad * 4 + r) * 32 + 16 * nt + l15] = ee[r];
                }
            }
        } else {
            // ---------------- conv + rg (waves 2,3; 16 rows each) -------
            int wid2 = wid - 2;
#pragma unroll
            for (int rep = 0; rep < 2; ++rep) {
                int task = rep * 64 + lane;            // 128 tasks = 16 rows x 8 k
                int rl = wid2 * 16 + (task >> 3);
                int k  = task & 7;
                float s = conv_b[k];
                for (int w = 0; w < 32; ++w) s += xs[w * 32 + rl] * conv_w[k * 32 + w];
                float l0 = convl_b[k], l1 = l0;
                for (int tt = 0; tt < 16; ++tt) {
                    float wv = convl_w[k * 16 + tt];
                    l0 += xs[(2 * tt) * 32 + rl] * wv;
                    l1 += xs[(2 * tt + 1) * 32 + rl] * wv;
                }
                rrs[rl * 25 + k * 3 + 0] = fmaxf(s, 0.f);
                rrs[rl * 25 + k * 3 + 1] = fmaxf(l0, 0.f);
                rrs[rl * 25 + k * 3 + 2] = fmaxf(l1, 0.f);
            }
            // intra-wave LDS RAW: in-order DS per wave; no cross-wave dep
            __builtin_amdgcn_wave_barrier();
            int rl = wid2 * 16 + (lane & 15);
            int nb = lane >> 4;
#pragma unroll
            for (int q = 0; q < 16; ++q) {
                int n = nb * 16 + q;
                float acc = 0.f;
#pragma unroll
                for (int c = 0; c < 24; ++c) acc += rrs[rl * 25 + c] * gc1_w[c * 64 + n];
                rgT[b * 32768 + n * 512 + mb + rl] = f2bf(acc);
            }
        }
    } else if (blk < 512) {
        // ---------------- Wb transpose ----------------
        int bid = blk - 256;
        int nb = (bid & 15) * 32, kb = (bid >> 4) * 32;
        float* tile = (float*)smem;             // [32][33]
        for (int u = t; u < 1024; u += 256) {
            int r = u >> 5, c = u & 31;
            tile[r * 33 + c] = Wb[(kb + r) * 512 + nb + c];
        }
        __syncthreads();
        for (int u = t; u < 1024; u += 256) {
            int r = u >> 5, c = u & 31;
            WbT[(nb + r) * 512 + kb + c] = f2bf(tile[c * 33 + r]);
        }
    } else {
        nrmss[(blk - 512) * 256 + t] = 0.f;
    }
}

// ---------------- K2: a_mx 4x4/thread, factorized exp, fused sumsq --------
__global__ __launch_bounds__(256) void amx_kernel(
    const float* __restrict__ e1, const float* __restrict__ e2,
    const float* __restrict__ b1p, const float* __restrict__ Vp,
    const float* __restrict__ bvp, unsigned short* __restrict__ amxb,
    float* __restrict__ nrmss)
{
    int bb = blockIdx.z;
    int i0 = blockIdx.y * 64, j0 = blockIdx.x * 64;
    __shared__ float e2s[64][33], e1s[64][33];
    __shared__ float Vs[32];
    __shared__ float red[16][68];
    int t = threadIdx.x;
    for (int u = t; u < 2048; u += 256) {
        int r = u >> 5, c = u & 31;
        e2s[r][c] = e2[(bb * 512 + i0 + r) * 32 + c];
        e1s[r][c] = e1[(bb * 512 + j0 + r) * 32 + c] + b1p[c];
    }
    if (t < 32) Vs[t] = Vp[t];
    __syncthreads();
    int ti = (t >> 4) * 4, tj = (t & 15) * 4;
    float acc[4][4] = {};
#pragma unroll
    for (int h = 0; h < 32; ++h) {
        float vv = Vs[h];
        float xi[4], yj[4], Exi[4], Eyj[4];
#pragma unroll
        for (int p = 0; p < 4; ++p) { xi[p] = e2s[ti + p][h]; Exi[p] = __expf(xi[p]); }
#pragma unroll
        for (int q = 0; q < 4; ++q) { yj[q] = e1s[tj + q][h]; Eyj[q] = __expf(yj[q]); }
#pragma unroll
        for (int p = 0; p < 4; ++p)
#pragma unroll
            for (int q = 0; q < 4; ++q) {
                float v = xi[p] + yj[q];
                float prod = Exi[p] * Eyj[q];
                float el = v > 0.f ? v : prod - 1.f;  // exp(xi+yj)=Exi*Eyj
                acc[p][q] += vv * el;
            }
    }
    float bv = bvp[0];
    float ss[4] = {0.f, 0.f, 0.f, 0.f};
#pragma unroll
    for (int p = 0; p < 4; ++p) {
        float v0 = acc[p][0] + bv, v1 = acc[p][1] + bv;
        float v2 = acc[p][2] + bv, v3 = acc[p][3] + bv;
        ushort4 o;
        o.x = f2bf(v0); o.y = f2bf(v1); o.z = f2bf(v2); o.w = f2bf(v3);
        *(ushort4*)(amxb + (bb * 512 + i0 + ti + p) * 512 + j0 + tj) = o;
        ss[0] += v0 * v0; ss[1] += v1 * v1; ss[2] += v2 * v2; ss[3] += v3 * v3;
    }
#pragma unroll
    for (int q = 0; q < 4; ++q) red[t >> 4][tj + q] = ss[q];
    __syncthreads();
    if (t < 64) {
        float s = 0.f;
#pragma unroll
        for (int g = 0; g < 16; ++g) s += red[g][t];
        atomicAdd(&nrmss[bb * 512 + j0 + t], s);
    }
}

// ---------------- K3: gemm_adjmix, wrap-ordered K so last A-tile == j0 ----
__global__ __launch_bounds__(256) void gemm_adjmix(
    const unsigned short* __restrict__ amxb, const unsigned short* __restrict__ WbT,
    const float* __restrict__ wbp, const float* __restrict__ adj,
    const float* __restrict__ nrmss, unsigned short* __restrict__ adjmix)
{
    int bb = blockIdx.z;
    int i0 = blockIdx.y * 64, j0 = blockIdx.x * 64;
    __shared__ __align__(16) short As[64 * 72];
    __shared__ __align__(16) short Bs[64 * 72];
    __shared__ float rn[512];
    int t = threadIdx.x, w = t >> 6, lane = t & 63;
    int l15 = lane & 15, quad = lane >> 4;
    for (int u = t; u < 512; u += 256)
        rn[u] = 1.f / fmaxf(sqrtf(nrmss[bb * 512 + u]), 1e-12f);
    const unsigned short* Ag = amxb + bb * 262144;
    f32x4 acc[4] = {};
    for (int kk = 1; kk <= 8; ++kk) {
        int k0 = (j0 + 64 * kk) & 511;      // last iter: k0 == j0
        __syncthreads();
#pragma unroll
        for (int u0 = 0; u0 < 2; ++u0) {
            int u = t + u0 * 256;
            int i = u >> 3, o = u & 7;
            *(int4*)(Bs + i * 72 + o * 8) =
                *(const int4*)(WbT + (j0 + i) * 512 + k0 + o * 8);
            union { int4 v; unsigned short us[8]; } ur;
            ur.v = *(const int4*)(Ag + (i0 + i) * 512 + k0 + o * 8);
            union { int4 v; unsigned short us[8]; } ow;
#pragma unroll
            for (int c = 0; c < 8; ++c)
                ow.us[c] = f2bf(bf2f(ur.us[c]) * rn[k0 + o * 8 + c]);
            *(int4*)(As + i * 72 + o * 8) = ow.v;
        }
        __syncthreads();
        bf16x8 a0 = *(bf16x8*)(As + (16 * w + l15) * 72 + quad * 8);
        bf16x8 a1 = *(bf16x8*)(As + (16 * w + l15) * 72 + 32 + quad * 8);
#pragma unroll
        for (int nt = 0; nt < 4; ++nt) {
            bf16x8 b0 = *(bf16x8*)(Bs + (16 * nt + l15) * 72 + quad * 8);
            bf16x8 b1 = *(bf16x8*)(Bs + (16 * nt + l15) * 72 + 32 + quad * 8);
            acc[nt] = MFMA16(a0, b0, acc[nt], 0, 0, 0);
            acc[nt] = MFMA16(a1, b1, acc[nt], 0, 0, 0);
        }
    }
    // As now holds scaled amx(i0:64, j0:64) in LDS
    float wb = wbp[0];
#pragma unroll
    for (int nt = 0; nt < 4; ++nt)
#pragma unroll
    for (int r = 0; r < 4; ++r) {
        int il = 16 * w + quad * 4 + r;
        int jl = 16 * nt + l15;
        int i = i0 + il, j = j0 + jl;
        float s  = acc[nt][r] + wb;
        float cv = 1.f / (1.f + __expf(-s));
        float am = bf2f((unsigned short)As[il * 72 + jl]);
        float ad = adj[i * 512 + j];
        adjmix[(bb * 512 + i) * 512 + j] = f2bf(ad * cv + am * (1.f - cv));
    }
}

// ---------------- K4: gemm_h1 + fused h1g = h1 @ gc2_w --------------------
__global__ __launch_bounds__(256) void gemm_h1(
    const unsigned short* __restrict__ adjmix, const unsigned short* __restrict__ rgT,
    const float* __restrict__ gc1_b, const float* __restrict__ gc2_w,
    float* __restrict__ h1g)
{
    int bb = blockIdx.y;
    int i0 = blockIdx.x * 32;
    __shared__ __align__(16) short As[32 * 72];
    __shared__ __align__(16) short Bs[64 * 72];
    __shared__ float h1s[32][72];
    int t = threadIdx.x, w = t >> 6, lane = t & 63;
    int l15 = lane & 15, quad = lane >> 4;
    int rt = w & 1, ntb = (w >> 1) * 2;
    const unsigned short* Ag = adjmix + bb * 262144;
    const unsigned short* Bg = rgT + bb * 32768;
    f32x4 acc[2] = {};
    for (int k0 = 0; k0 < 512; k0 += 64) {
        __syncthreads();
        {
            int i = t >> 3, o = t & 7;
            *(int4*)(As + i * 72 + o * 8) =
                *(const int4*)(Ag + (i0 + i) * 512 + k0 + o * 8);
        }
#pragma unroll
        for (int u0 = 0; u0 < 2; ++u0) {
            int u = t + u0 * 256;
            int i = u >> 3, o = u & 7;
            *(int4*)(Bs + i * 72 + o * 8) =
                *(const int4*)(Bg + i * 512 + k0 + o * 8);
        }
        __syncthreads();
        bf16x8 a0 = *(bf16x8*)(As + (16 * rt + l15) * 72 + quad * 8);
        bf16x8 a1 = *(bf16x8*)(As + (16 * rt + l15) * 72 + 32 + quad * 8);
#pragma unroll
        for (int q = 0; q < 2; ++q) {
            int nt = ntb + q;
            bf16x8 b0 = *(bf16x8*)(Bs + (16 * nt + l15) * 72 + quad * 8);
            bf16x8 b1 = *(bf16x8*)(Bs + (16 * nt + l15) * 72 + 32 + quad * 8);
            acc[q] = MFMA16(a0, b0, acc[q], 0, 0, 0);
            acc[q] = MFMA16(a1, b1, acc[q], 0, 0, 0);
        }
    }
#pragma unroll
    for (int q = 0; q < 2; ++q)
#pragma unroll
    for (int r = 0; r < 4; ++r) {
        int il = 16 * rt + quad * 4 + r;
        int j = 16 * (ntb + q) + l15;
        h1s[il][j] = fmaxf(acc[q][r] + gc1_b[j], 0.f);
    }
    __syncthreads();
    for (int u = t; u < 320; u += 256) {
        int row = u / 10, ns = u - row * 10;
        float a2 = 0.f;
#pragma unroll
        for (int j = 0; j < 64; ++j) a2 += h1s[row][j] * gc2_w[j * 10 + ns];
        h1g[(bb * 512 + i0 + row) * 10 + ns] = a2;
    }
}

// ---------------- K5: ospout, 16 rows/block -------------------------------
__global__ __launch_bounds__(256) void ospout_kernel(
    const unsigned short* __restrict__ adjmix, const float* __restrict__ h1g,
    const float* __restrict__ gc2_b, const float* __restrict__ lh,
    const float* __restrict__ out_w, const float* __restrict__ out_b,
    float* __restrict__ out)
{
    int r0 = blockIdx.x * 16;
    int bb = r0 >> 9;
    int wid = threadIdx.x >> 6, lane = threadIdx.x & 63;
    __shared__ float Bsm[10][512];
    __shared__ float ow[8][80];
    __shared__ float ob[8], g2b[10];
    for (int u = threadIdx.x; u < 5120; u += 256) {
        int k = u / 10, ns = u - k * 10;
        Bsm[ns][k] = h1g[bb * 5120 + u];
    }
    if (threadIdx.x < 8)  ob[threadIdx.x]  = out_b[threadIdx.x];
    if (threadIdx.x < 10) g2b[threadIdx.x] = gc2_b[threadIdx.x];
    for (int u = threadIdx.x; u < 592; u += 256) {
        int hh = u / 74, c = u - hh * 74;
        ow[hh][c] = out_w[u];
    }
    __syncthreads();
#pragma unroll
    for (int half = 0; half < 4; ++half) {
        int row = r0 + half * 4 + wid, m = row & 511;
        const unsigned short* Ar = adjmix + row * 512;
        float a[8];
#pragma unroll
        for (int q = 0; q < 8; ++q) a[q] = bf2f(Ar[lane + 64 * q]);
        float os[10];
#pragma unroll
        for (int ns = 0; ns < 10; ++ns) {
            float s = 0.f;
#pragma unroll
            for (int q = 0; q < 8; ++q) s += a[q] * Bsm[ns][lane + 64 * q];
#pragma unroll
            for (int off = 32; off; off >>= 1) s += __shfl_xor(s, off);
            os[ns] = fmaxf(s + g2b[ns], 0.f);
        }
        float lv = lh[row * 64 + lane];
#pragma unroll
        for (int hh = 0; hh < 8; ++hh) {
            float t1 = lv * ow[hh][10 + lane];
#pragma unroll
            for (int off = 32; off; off >>= 1) t1 += __shfl_xor(t1, off);
            if (lane == hh) {
                float acc = ob[hh] + t1;
#pragma unroll
                for (int ns = 0; ns < 10; ++ns) acc += os[ns] * ow[hh][ns];
                out[bb * 4096 + hh * 512 + m] = acc;
            }
        }
    }
}

// ---------------- launch ---------------------------------------------------
extern "C" void kernel_launch(void* const* d_in, const int* in_sizes, int n_in,
                              void* d_out, int out_size, void* d_ws, size_t ws_size,
                              hipStream_t stream)
{
    const float* x       = (const float*)d_in[0];
    const float* adj     = (const float*)d_in[1];
    const float* Wih     = (const float*)d_in[2];
    const float* Whh     = (const float*)d_in[3];
    const float* bih     = (const float*)d_in[4];
    const float* bhh     = (const float*)d_in[5];
    const float* W1      = (const float*)d_in[6];
    const float* W2      = (const float*)d_in[7];
    const float* b1      = (const float*)d_in[8];
    const float* V       = (const float*)d_in[9];
    const float* bv      = (const float*)d_in[10];
    const float* Wb      = (const float*)d_in[11];
    const float* wb      = (const float*)d_in[12];
    const float* conv_w  = (const float*)d_in[13];
    const float* conv_b  = (const float*)d_in[14];
    const float* convl_w = (const float*)d_in[15];
    const float* convl_b = (const float*)d_in[16];
    const float* gc1_w   = (const float*)d_in[17];
    const float* gc1_b   = (const float*)d_in[18];
    const float* gc2_w   = (const float*)d_in[19];
    const float* gc2_b   = (const float*)d_in[20];
    const float* out_w   = (const float*)d_in[21];
    const float* out_b   = (const float*)d_in[22];

    float* ws    = (float*)d_ws;
    float* lh    = ws;                  // 524288
    float* e1    = lh + 524288;         // 262144
    float* e2    = e1 + 262144;         // 262144
    float* nrmss = e2 + 262144;         // 8192
    float* h1g   = nrmss + 8192;        // 81920
    unsigned short* amxb    = (unsigned short*)(h1g + 81920);  // 4194304
    unsigned short* adjmixb = amxb + 4194304;                  // 4194304
    unsigned short* WbT     = adjmixb + 4194304;               // 262144
    unsigned short* rgT     = WbT + 262144;                    // 524288

    fused1_kernel<<<544, 256, 0, stream>>>(
        x, Wih, Whh, bih, bhh, W1, W2, lh, e1, e2,
        conv_w, conv_b, convl_w, convl_b, gc1_w, rgT, Wb, WbT, nrmss);
    amx_kernel<<<dim3(8, 8, 16), 256, 0, stream>>>(e1, e2, b1, V, bv,
                                                   amxb, nrmss);
    gemm_adjmix<<<dim3(8, 8, 16), 256, 0, stream>>>(amxb, WbT, wb, adj,
                                                    nrmss, adjmixb);
    gemm_h1<<<dim3(16, 16), 256, 0, stream>>>(adjmixb, rgT, gc1_b, gc2_w, h1g);
    ospout_kernel<<<512, 256, 0, stream>>>(adjmixb, h1g, gc2_b, lh,
                                           out_w, out_b, (float*)d_out);
}